// Round 1
// baseline (509.714 us; speedup 1.0000x reference)
//
#include <hip/hip_runtime.h>
#include <cstdint>
#include <cstddef>

// PointNet++ Feature Propagation, fused pipeline.
// B=8, N=4096, S=1024, D1=128, D2=256, IN_C=384, MLP=[256,256], BN training-mode.
//
// Pipeline:
//  1. transpose W1/W2 -> Wt [K][256] (coalesced float4 reads in GEMM)
//     transpose points2/colors2 -> [B][S][D2] (contiguous-D gather)
//  2. top3: per (b,n) 3 nearest xyz2 + inverse-distance weights (shared p/c)
//  3. gemm1: X = [points1^T | interp] @ W1t, fused gather staging; writes raw Y1
//     + per-block channel sum/sumsq partials (deterministic)
//  4. reduce_stats: mean/var -> folded scale/shift (bias skipped: cancels in BN)
//  5. gemm2: stage relu(bn(Y1)) -> @ W2t, raw y2 written TRANSPOSED to d_out,
//     + stats partials
//  6. reduce_stats layer2
//  7. bnfinal: in-place relu(y2*scale+shift) over d_out
//
// ws layout (bytes):
//   idx      0         393,216   (32768*3 int)
//   wgt      393,216   393,216
//   p2t      786,432   8,388,608
//   c2t      9,175,040 8,388,608
//   Wt1      17,563,648  786,432  ([2][384][256])
//   Wt2      18,350,080  524,288  ([2][256][256])
//   ss       18,874,368  8,192    (scale/shift [layer][{sc,sh}][t][256])
//   psum/psq 18,882,560  4,194,304 ([2][1024][256] x2, reused layer1/2)
//   Y1       23,076,864  67,108,864 ([2][32768][256])
//   total ~90.2 MB

#define B_   8
#define N_   4096
#define S_   1024
#define D1_  128
#define D2_  256
#define INC_ 384
#define OC_  256
#define M_   (B_ * N_)          // 32768
#define TILE_M 32
#define KC   16
#define NBLK (M_ / TILE_M)      // 1024

// ---------------------------------------------------------------- transpose
__global__ __launch_bounds__(256) void transpose_kernel(
    const float* __restrict__ src, float* __restrict__ dst, int R, int C)
{
    __shared__ float tile[32][33];
    const float* s = src + (size_t)blockIdx.z * R * C;
    float*       d = dst + (size_t)blockIdx.z * R * C;
    int c = blockIdx.x * 32 + threadIdx.x;
#pragma unroll
    for (int i = 0; i < 4; ++i) {
        int r = blockIdx.y * 32 + threadIdx.y + i * 8;
        tile[threadIdx.y + i * 8][threadIdx.x] = s[(size_t)r * C + c];
    }
    __syncthreads();
    int r2 = blockIdx.y * 32 + threadIdx.x;
#pragma unroll
    for (int i = 0; i < 4; ++i) {
        int c2 = blockIdx.x * 32 + threadIdx.y + i * 8;
        d[(size_t)c2 * R + r2] = tile[threadIdx.x][threadIdx.y + i * 8];
    }
}

// ---------------------------------------------------------------- top-3 NN
__global__ __launch_bounds__(256) void top3_kernel(
    const float* __restrict__ xyz1, const float* __restrict__ xyz2,
    int* __restrict__ idxo, float* __restrict__ wo)
{
    __shared__ float sx[S_], sy[S_], sz[S_], sn[S_];
    const int b = blockIdx.y;
    const int n = blockIdx.x * 256 + threadIdx.x;
    const float* x2 = xyz2 + (size_t)b * 3 * S_;
    for (int s = threadIdx.x; s < S_; s += 256) {
        float xs = x2[s], ys = x2[S_ + s], zs = x2[2 * S_ + s];
        sx[s] = xs; sy[s] = ys; sz[s] = zs;
        sn[s] = xs * xs + ys * ys + zs * zs;
    }
    __syncthreads();
    const float* x1 = xyz1 + (size_t)b * 3 * N_;
    const float xq = x1[n], yq = x1[N_ + n], zq = x1[2 * N_ + n];
    const float n1 = xq * xq + yq * yq + zq * zq;
    float d0 = 3.4e38f, d1 = 3.4e38f, d2 = 3.4e38f;
    int   i0 = 0, i1 = 0, i2 = 0;
    for (int s = 0; s < S_; ++s) {
        float dot = xq * sx[s] + yq * sy[s] + zq * sz[s];
        float d   = (n1 - 2.0f * dot) + sn[s];
        // strict < : ties keep the earlier index (matches stable lax.top_k)
        if (d < d2) {
            if (d < d1) {
                d2 = d1; i2 = i1;
                if (d < d0) { d1 = d0; i1 = i0; d0 = d; i0 = s; }
                else        { d1 = d;  i1 = s; }
            } else { d2 = d; i2 = s; }
        }
    }
    float r0 = 1.f / (d0 + 1e-8f);
    float r1 = 1.f / (d1 + 1e-8f);
    float r2 = 1.f / (d2 + 1e-8f);
    float rs = r0 + r1 + r2;
    int base = (b * N_ + n) * 3;
    idxo[base] = i0; idxo[base + 1] = i1; idxo[base + 2] = i2;
    wo[base] = r0 / rs; wo[base + 1] = r1 / rs; wo[base + 2] = r2 / rs;
}

// ---------------------------------------------------------------- GEMM layer 1
// grid (NBLK, 2): x = row tile (32 rows), y = tensor (0=points, 1=colors)
__global__ __launch_bounds__(256) void gemm1_kernel(
    const float* __restrict__ points1, const float* __restrict__ colors1,
    const float* __restrict__ p2t,     const float* __restrict__ c2t,
    const int*   __restrict__ idxw,    const float* __restrict__ wgtw,
    const float* __restrict__ Wt1,
    float* __restrict__ Y1, float* __restrict__ psum, float* __restrict__ psq)
{
    const int t   = blockIdx.y;
    const int blk = blockIdx.x;
    const int m0  = blk * TILE_M;
    const int b   = m0 >> 12;
    const int n0  = m0 & (N_ - 1);
    const float* x1  = t ? colors1 : points1;
    const float* f2t = t ? c2t : p2t;
    const float* Wt  = Wt1 + (size_t)t * (INC_ * OC_);

    __shared__ __align__(16) float Xs[TILE_M][KC + 4];
    __shared__ float ps[4][OC_], pq[4][OC_];

    const int tid = threadIdx.x;
    const int c0  = tid & 63;
    const int rg  = tid >> 6;
    const int kB  = tid & 15;
    const int rB  = tid >> 4;   // 0..15
    const int rA  = tid & 31;
    const int kA  = tid >> 5;   // 0..7

    // hoist gather indices/weights for this thread's staging rows
    int   ia[2][3]; float wa[2][3];
#pragma unroll
    for (int h = 0; h < 2; ++h) {
        int n = b * N_ + n0 + rB + 16 * h;
#pragma unroll
        for (int j = 0; j < 3; ++j) { ia[h][j] = idxw[n * 3 + j]; wa[h][j] = wgtw[n * 3 + j]; }
    }

    float acc[8][4];
#pragma unroll
    for (int i = 0; i < 8; ++i)
#pragma unroll
        for (int j = 0; j < 4; ++j) acc[i][j] = 0.f;

    for (int kc = 0; kc < INC_; kc += KC) {
        __syncthreads();
        if (kc < D1_) {
            // X[:, k] = points1[b, kc+k, n0+r]  (contiguous along r)
#pragma unroll
            for (int h = 0; h < 2; ++h) {
                int k = kA + 8 * h;
                Xs[rA][k] = x1[(size_t)(b * D1_ + kc + k) * N_ + n0 + rA];
            }
        } else {
            // X[:, k] = sum_j w_j * f2t[b, idx_j, kc-128+k]  (contiguous along k)
            int d0 = kc - D1_;
#pragma unroll
            for (int h = 0; h < 2; ++h) {
                int rr = rB + 16 * h;
                float v = wa[h][0] * f2t[((size_t)b * S_ + ia[h][0]) * D2_ + d0 + kB]
                        + wa[h][1] * f2t[((size_t)b * S_ + ia[h][1]) * D2_ + d0 + kB]
                        + wa[h][2] * f2t[((size_t)b * S_ + ia[h][2]) * D2_ + d0 + kB];
                Xs[rr][kB] = v;
            }
        }
        __syncthreads();
        const float* WtC = Wt + (size_t)kc * OC_ + c0 * 4;
#pragma unroll
        for (int k4 = 0; k4 < KC; k4 += 4) {
            float xv[8][4];
#pragma unroll
            for (int i = 0; i < 8; ++i)
                *(float4*)xv[i] = *(const float4*)&Xs[rg * 8 + i][k4];
#pragma unroll
            for (int kk = 0; kk < 4; ++kk) {
                float4 w4 = *(const float4*)(WtC + (size_t)(k4 + kk) * OC_);
#pragma unroll
                for (int i = 0; i < 8; ++i) {
                    acc[i][0] = fmaf(xv[i][kk], w4.x, acc[i][0]);
                    acc[i][1] = fmaf(xv[i][kk], w4.y, acc[i][1]);
                    acc[i][2] = fmaf(xv[i][kk], w4.z, acc[i][2]);
                    acc[i][3] = fmaf(xv[i][kk], w4.w, acc[i][3]);
                }
            }
        }
    }

    // raw Y1 (row-major [t][m][c]) -- coalesced float4
    size_t ybase = ((size_t)t * M_ + m0) * OC_;
#pragma unroll
    for (int i = 0; i < 8; ++i) {
        float4 v = make_float4(acc[i][0], acc[i][1], acc[i][2], acc[i][3]);
        *(float4*)(Y1 + ybase + (size_t)(rg * 8 + i) * OC_ + c0 * 4) = v;
    }
    // per-block channel stats partials (deterministic)
#pragma unroll
    for (int j = 0; j < 4; ++j) {
        float s = 0.f, q = 0.f;
#pragma unroll
        for (int i = 0; i < 8; ++i) { s += acc[i][j]; q += acc[i][j] * acc[i][j]; }
        ps[rg][c0 * 4 + j] = s;
        pq[rg][c0 * 4 + j] = q;
    }
    __syncthreads();
    {
        int c = tid;
        float s = ps[0][c] + ps[1][c] + ps[2][c] + ps[3][c];
        float q = pq[0][c] + pq[1][c] + pq[2][c] + pq[3][c];
        psum[((size_t)t * NBLK + blk) * OC_ + c] = s;
        psq [((size_t)t * NBLK + blk) * OC_ + c] = q;
    }
}

// ---------------------------------------------------------------- stats reduce
__global__ __launch_bounds__(256) void reduce_stats_kernel(
    const float* __restrict__ psum, const float* __restrict__ psq,
    const float* __restrict__ g_p,  const float* __restrict__ be_p,
    const float* __restrict__ g_c,  const float* __restrict__ be_c,
    float* __restrict__ ss, int layer)
{
    const int t = blockIdx.x;
    const int c = threadIdx.x;
    const float* sp = psum + (size_t)t * NBLK * OC_ + c;
    const float* qp = psq  + (size_t)t * NBLK * OC_ + c;
    float s = 0.f, q = 0.f;
    for (int i = 0; i < NBLK; ++i) { s += sp[(size_t)i * OC_]; q += qp[(size_t)i * OC_]; }
    float mean = s * (1.f / (float)M_);
    float var  = q * (1.f / (float)M_) - mean * mean;
    float inv  = rsqrtf(var + 1e-5f);
    const float* g  = t ? g_c  : g_p;
    const float* be = t ? be_c : be_p;
    float sc = g[c] * inv;
    float sh = be[c] - mean * sc;
    ss[layer * 1024 + t * OC_ + c]       = sc;
    ss[layer * 1024 + 512 + t * OC_ + c] = sh;
}

// ---------------------------------------------------------------- GEMM layer 2
__global__ __launch_bounds__(256) void gemm2_kernel(
    const float* __restrict__ Y1, const float* __restrict__ Wt2,
    const float* __restrict__ ss, float* __restrict__ out,
    float* __restrict__ psum, float* __restrict__ psq)
{
    const int t   = blockIdx.y;
    const int blk = blockIdx.x;
    const int m0  = blk * TILE_M;
    const int b   = m0 >> 12;
    const int n0  = m0 & (N_ - 1);
    const float* Wt  = Wt2 + (size_t)t * (OC_ * OC_);
    const float* sc1 = ss + t * OC_;
    const float* sh1 = ss + 512 + t * OC_;

    __shared__ __align__(16) float Xs[TILE_M][KC + 4];
    __shared__ float ps[4][OC_], pq[4][OC_];
    __shared__ float outs[TILE_M][OC_ + 1];

    const int tid = threadIdx.x;
    const int c0  = tid & 63;
    const int rg  = tid >> 6;
    const int kB  = tid & 15;
    const int rB  = tid >> 4;

    float acc[8][4];
#pragma unroll
    for (int i = 0; i < 8; ++i)
#pragma unroll
        for (int j = 0; j < 4; ++j) acc[i][j] = 0.f;

    for (int kc = 0; kc < OC_; kc += KC) {
        __syncthreads();
#pragma unroll
        for (int h = 0; h < 2; ++h) {
            int rr = rB + 16 * h;
            float y = Y1[((size_t)t * M_ + m0 + rr) * OC_ + kc + kB];
            Xs[rr][kB] = fmaxf(0.f, fmaf(y, sc1[kc + kB], sh1[kc + kB]));
        }
        __syncthreads();
        const float* WtC = Wt + (size_t)kc * OC_ + c0 * 4;
#pragma unroll
        for (int k4 = 0; k4 < KC; k4 += 4) {
            float xv[8][4];
#pragma unroll
            for (int i = 0; i < 8; ++i)
                *(float4*)xv[i] = *(const float4*)&Xs[rg * 8 + i][k4];
#pragma unroll
            for (int kk = 0; kk < 4; ++kk) {
                float4 w4 = *(const float4*)(WtC + (size_t)(k4 + kk) * OC_);
#pragma unroll
                for (int i = 0; i < 8; ++i) {
                    acc[i][0] = fmaf(xv[i][kk], w4.x, acc[i][0]);
                    acc[i][1] = fmaf(xv[i][kk], w4.y, acc[i][1]);
                    acc[i][2] = fmaf(xv[i][kk], w4.z, acc[i][2]);
                    acc[i][3] = fmaf(xv[i][kk], w4.w, acc[i][3]);
                }
            }
        }
    }

    // stats partials on raw y2
#pragma unroll
    for (int j = 0; j < 4; ++j) {
        float s = 0.f, q = 0.f;
#pragma unroll
        for (int i = 0; i < 8; ++i) { s += acc[i][j]; q += acc[i][j] * acc[i][j]; }
        ps[rg][c0 * 4 + j] = s;
        pq[rg][c0 * 4 + j] = q;
    }
    // stage for transposed store
#pragma unroll
    for (int i = 0; i < 8; ++i)
#pragma unroll
        for (int j = 0; j < 4; ++j)
            outs[rg * 8 + i][c0 * 4 + j] = acc[i][j];
    __syncthreads();
    {
        int c = tid;
        float s = ps[0][c] + ps[1][c] + ps[2][c] + ps[3][c];
        float q = pq[0][c] + pq[1][c] + pq[2][c] + pq[3][c];
        psum[((size_t)t * NBLK + blk) * OC_ + c] = s;
        psq [((size_t)t * NBLK + blk) * OC_ + c] = q;
    }
    // transposed store: raw y2 -> d_out [t][b][o][n]
    const int lane = tid & 63;
    const int w    = tid >> 6;
    const int osub = lane >> 3;
    const int nl   = (lane & 7) * 4;
    float* obase = out + ((size_t)t * B_ + b) * ((size_t)OC_ * N_) + n0 + nl;
#pragma unroll
    for (int it = 0; it < 8; ++it) {
        int o = w * 64 + it * 8 + osub;
        float4 v = make_float4(outs[nl][o], outs[nl + 1][o], outs[nl + 2][o], outs[nl + 3][o]);
        *(float4*)(obase + (size_t)o * N_) = v;
    }
}

// ---------------------------------------------------------------- final BN+ReLU
__global__ __launch_bounds__(256) void bnfinal_kernel(
    float* __restrict__ out, const float* __restrict__ ss)
{
    const int total4 = 2 * B_ * OC_ * N_ / 4;   // 4,194,304
    for (int i4 = blockIdx.x * blockDim.x + threadIdx.x; i4 < total4;
         i4 += gridDim.x * blockDim.x) {
        size_t i = (size_t)i4 * 4;
        int o = (int)((i >> 12) & 255);
        int t = (int)(i >> 23);
        float sc = ss[1024 + t * OC_ + o];
        float sh = ss[1536 + t * OC_ + o];
        float4 v = ((float4*)out)[i4];
        v.x = fmaxf(0.f, fmaf(v.x, sc, sh));
        v.y = fmaxf(0.f, fmaf(v.y, sc, sh));
        v.z = fmaxf(0.f, fmaf(v.z, sc, sh));
        v.w = fmaxf(0.f, fmaf(v.w, sc, sh));
        ((float4*)out)[i4] = v;
    }
}

// ---------------------------------------------------------------- launch
extern "C" void kernel_launch(void* const* d_in, const int* in_sizes, int n_in,
                              void* d_out, int out_size, void* d_ws, size_t ws_size,
                              hipStream_t stream)
{
    const float* xyz1    = (const float*)d_in[0];
    const float* xyz2    = (const float*)d_in[1];
    const float* points1 = (const float*)d_in[2];
    const float* points2 = (const float*)d_in[3];
    const float* colors1 = (const float*)d_in[4];
    const float* colors2 = (const float*)d_in[5];
    const float* Wp1  = (const float*)d_in[6];
    const float* gp1  = (const float*)d_in[8];
    const float* bep1 = (const float*)d_in[9];
    const float* Wc1  = (const float*)d_in[10];
    const float* gc1  = (const float*)d_in[12];
    const float* bec1 = (const float*)d_in[13];
    const float* Wp2  = (const float*)d_in[14];
    const float* gp2  = (const float*)d_in[16];
    const float* bep2 = (const float*)d_in[17];
    const float* Wc2  = (const float*)d_in[18];
    const float* gc2  = (const float*)d_in[20];
    const float* bec2 = (const float*)d_in[21];
    // biases bp1/bc1/bp2/bc2 (d_in[7,11,15,19]) intentionally unused:
    // a constant channel shift cancels exactly in training-mode BN.

    char* ws = (char*)d_ws;
    int*   idxw = (int*)  (ws + 0);
    float* wgtw = (float*)(ws + 393216);
    float* p2t  = (float*)(ws + 786432);
    float* c2t  = (float*)(ws + 9175040);
    float* Wt1  = (float*)(ws + 17563648);
    float* Wt2  = (float*)(ws + 18350080);
    float* ssb  = (float*)(ws + 18874368);
    float* psum = (float*)(ws + 18882560);
    float* psq  = psum + 2 * NBLK * OC_;
    float* Y1   = (float*)(ws + 23076864);
    float* out  = (float*)d_out;

    dim3 tb(32, 8);
    transpose_kernel<<<dim3(12, 8, 1), tb, 0, stream>>>(Wp1, Wt1,          256, 384);
    transpose_kernel<<<dim3(12, 8, 1), tb, 0, stream>>>(Wc1, Wt1 + 98304,  256, 384);
    transpose_kernel<<<dim3(8, 8, 1),  tb, 0, stream>>>(Wp2, Wt2,          256, 256);
    transpose_kernel<<<dim3(8, 8, 1),  tb, 0, stream>>>(Wc2, Wt2 + 65536,  256, 256);
    transpose_kernel<<<dim3(32, 8, 8), tb, 0, stream>>>(points2, p2t,      256, 1024);
    transpose_kernel<<<dim3(32, 8, 8), tb, 0, stream>>>(colors2, c2t,      256, 1024);

    top3_kernel<<<dim3(16, 8), 256, 0, stream>>>(xyz1, xyz2, idxw, wgtw);

    gemm1_kernel<<<dim3(NBLK, 2), 256, 0, stream>>>(points1, colors1, p2t, c2t,
                                                    idxw, wgtw, Wt1, Y1, psum, psq);
    reduce_stats_kernel<<<2, 256, 0, stream>>>(psum, psq, gp1, bep1, gc1, bec1, ssb, 0);
    gemm2_kernel<<<dim3(NBLK, 2), 256, 0, stream>>>(Y1, Wt2, ssb, out, psum, psq);
    reduce_stats_kernel<<<2, 256, 0, stream>>>(psum, psq, gp2, bep2, gc2, bec2, ssb, 1);
    bnfinal_kernel<<<4096, 256, 0, stream>>>(out, ssb);
}

// Round 2
// 258.136 us; speedup vs baseline: 1.9746x; 1.9746x over previous
//
#include <hip/hip_runtime.h>
#include <cstdint>
#include <cstddef>

// PointNet++ FP, bf16-MFMA pipeline.
// B=8, N=4096, S=1024, D1=128, D2=256, IN_C=384, MLP=[256,256], BN training.
//
//  transpose p2t/c2t -> [B][S][D2]
//  convw: W* -> bf16 [o][k] (no transpose; MFMA A-operand wants k-contiguous)
//  top3:  3-NN idx + weights (shared by both tensors)
//  buildx: Xall[t][m][384] bf16 = [points1^T | interp]
//  gemm1: D[c][m] = W1 @ Xall^T  (16x16x32 bf16 MFMA), Y1[m][c] bf16 direct b64 stores
//  stats1/reduce1: channel mean/var of Y1 -> folded scale/shift (bias cancels in BN)
//  gemm2: B-operand staged with fused bn+relu, raw y2 -> d_out [t][b][o][n]
//  stats2: per-channel mean/var of y2 -> scale/shift
//  bnfinal: in-place relu(y2*sc+sh)
//
// ws layout (bytes), total 84,811,776 (< 90.2 MB proven):
//   Xall 0 .. 50331648 | Wb1 50331648 | Wb2 50724864 | ss 50987008
//   psum 50995200 | psq 51126272 | transient@51257344: p2t,c2t,idx,wgt
//   Y1 overlays transient @51257344 (33554432)

#define B_   8
#define N_   4096
#define S_   1024
#define D1_  128
#define D2_  256
#define INC_ 384
#define OC_  256
#define M_   (B_ * N_)

typedef __attribute__((ext_vector_type(8))) short sh8;
typedef __attribute__((ext_vector_type(4))) float f32x4;
typedef __attribute__((ext_vector_type(4))) unsigned short ush4;
typedef __attribute__((ext_vector_type(8))) unsigned short ush8;

__device__ __forceinline__ unsigned short bf16rne(float f) {
    union { float f; unsigned u; } v; v.f = f;
    return (unsigned short)((v.u + 0x7FFFu + ((v.u >> 16) & 1u)) >> 16);
}
__device__ __forceinline__ float bf2f(unsigned short h) {
    union { unsigned u; float f; } v; v.u = ((unsigned)h) << 16;
    return v.f;
}
__device__ __forceinline__ void gload16(const void* gsrc, void* lds) {
    __builtin_amdgcn_global_load_lds(
        (const __attribute__((address_space(1))) void*)gsrc,
        (__attribute__((address_space(3))) void*)lds, 16, 0, 0);
}

// ---------------------------------------------------------------- transpose
__global__ __launch_bounds__(256) void transpose_kernel(
    const float* __restrict__ src, float* __restrict__ dst, int R, int C)
{
    __shared__ float tile[32][33];
    const float* s = src + (size_t)blockIdx.z * R * C;
    float*       d = dst + (size_t)blockIdx.z * R * C;
    int c = blockIdx.x * 32 + threadIdx.x;
#pragma unroll
    for (int i = 0; i < 4; ++i) {
        int r = blockIdx.y * 32 + threadIdx.y + i * 8;
        tile[threadIdx.y + i * 8][threadIdx.x] = s[(size_t)r * C + c];
    }
    __syncthreads();
    int r2 = blockIdx.y * 32 + threadIdx.x;
#pragma unroll
    for (int i = 0; i < 4; ++i) {
        int c2 = blockIdx.x * 32 + threadIdx.y + i * 8;
        d[(size_t)c2 * R + r2] = tile[threadIdx.x][threadIdx.y + i * 8];
    }
}

// ---------------------------------------------------------------- W -> bf16
__global__ __launch_bounds__(256) void convw_kernel(
    const float* __restrict__ Wp1, const float* __restrict__ Wc1,
    const float* __restrict__ Wp2, const float* __restrict__ Wc2,
    unsigned short* __restrict__ Wb1, unsigned short* __restrict__ Wb2)
{
    int e = (blockIdx.x * 256 + threadIdx.x) * 4;
    const float* src; unsigned short* dst; int off;
    if (e < 98304)       { src = Wp1; dst = Wb1;          off = e; }
    else if (e < 196608) { src = Wc1; dst = Wb1 + 98304;  off = e - 98304; }
    else if (e < 262144) { src = Wp2; dst = Wb2;          off = e - 196608; }
    else                 { src = Wc2; dst = Wb2 + 65536;  off = e - 262144; }
    float4 v = *(const float4*)(src + off);
    ush4 o; o[0] = bf16rne(v.x); o[1] = bf16rne(v.y); o[2] = bf16rne(v.z); o[3] = bf16rne(v.w);
    *(ush4*)(dst + off) = o;
}

// ---------------------------------------------------------------- top-3 NN
__global__ __launch_bounds__(256) void top3_kernel(
    const float* __restrict__ xyz1, const float* __restrict__ xyz2,
    int* __restrict__ idxo, float* __restrict__ wo)
{
    __shared__ float sx[S_], sy[S_], sz[S_], sn[S_];
    const int b = blockIdx.y;
    const int n = blockIdx.x * 256 + threadIdx.x;
    const float* x2 = xyz2 + (size_t)b * 3 * S_;
    for (int s = threadIdx.x; s < S_; s += 256) {
        float xs = x2[s], ys = x2[S_ + s], zs = x2[2 * S_ + s];
        sx[s] = xs; sy[s] = ys; sz[s] = zs;
        sn[s] = xs * xs + ys * ys + zs * zs;
    }
    __syncthreads();
    const float* x1 = xyz1 + (size_t)b * 3 * N_;
    const float xq = x1[n], yq = x1[N_ + n], zq = x1[2 * N_ + n];
    const float n1 = xq * xq + yq * yq + zq * zq;
    float d0 = 3.4e38f, d1 = 3.4e38f, d2 = 3.4e38f;
    int   i0 = 0, i1 = 0, i2 = 0;
    for (int s = 0; s < S_; ++s) {
        float dot = xq * sx[s] + yq * sy[s] + zq * sz[s];
        float d   = (n1 - 2.0f * dot) + sn[s];
        if (d < d2) {
            if (d < d1) {
                d2 = d1; i2 = i1;
                if (d < d0) { d1 = d0; i1 = i0; d0 = d; i0 = s; }
                else        { d1 = d;  i1 = s; }
            } else { d2 = d; i2 = s; }
        }
    }
    float r0 = 1.f / (d0 + 1e-8f);
    float r1 = 1.f / (d1 + 1e-8f);
    float r2 = 1.f / (d2 + 1e-8f);
    float rs = r0 + r1 + r2;
    int base = (b * N_ + n) * 3;
    idxo[base] = i0; idxo[base + 1] = i1; idxo[base + 2] = i2;
    wo[base] = r0 / rs; wo[base + 1] = r1 / rs; wo[base + 2] = r2 / rs;
}

// ---------------------------------------------------------------- build X (bf16)
__global__ __launch_bounds__(256) void buildx_kernel(
    const float* __restrict__ points1, const float* __restrict__ colors1,
    const float* __restrict__ p2t, const float* __restrict__ c2t,
    const int* __restrict__ idxw, const float* __restrict__ wgtw,
    unsigned short* __restrict__ Xall)
{
    const int t = blockIdx.z, b = blockIdx.y, n0 = blockIdx.x * 64;
    const float* x1  = t ? colors1 : points1;
    const float* f2t = t ? c2t : p2t;
    const int tid = threadIdx.x;
    __shared__ float tileA[64][132];

    // part A: transpose x1[b][0:128][n0:n0+64] -> Xall[m][0:128]
#pragma unroll
    for (int it = 0; it < 8; ++it) {
        int fl4 = it * 256 + tid;
        int d = fl4 >> 4, nl = (fl4 & 15) * 4;
        float4 v = *(const float4*)(x1 + ((size_t)b * D1_ + d) * N_ + n0 + nl);
        tileA[nl][d] = v.x; tileA[nl + 1][d] = v.y; tileA[nl + 2][d] = v.z; tileA[nl + 3][d] = v.w;
    }
    __syncthreads();
    size_t mbase = (size_t)t * M_ + (size_t)b * N_ + n0;
#pragma unroll
    for (int it = 0; it < 4; ++it) {
        int e8 = it * 256 + tid;
        int r = e8 >> 4, dc = (e8 & 15) * 8;
        ush8 o;
#pragma unroll
        for (int j = 0; j < 8; ++j) o[j] = bf16rne(tileA[r][dc + j]);
        *(ush8*)(Xall + (mbase + r) * INC_ + dc) = o;
    }

    // part B: interp -> Xall[m][128:384]
    const int r = tid >> 2, qq = tid & 3;
    const int nb = (b * N_ + n0 + r) * 3;
    int i0 = idxw[nb], i1 = idxw[nb + 1], i2 = idxw[nb + 2];
    float w0 = wgtw[nb], w1 = wgtw[nb + 1], w2 = wgtw[nb + 2];
    const float* f0 = f2t + ((size_t)b * S_ + i0) * D2_;
    const float* f1 = f2t + ((size_t)b * S_ + i1) * D2_;
    const float* f2 = f2t + ((size_t)b * S_ + i2) * D2_;
#pragma unroll
    for (int c8 = 0; c8 < 8; ++c8) {
        int d2 = qq * 64 + c8 * 8;
        ush8 o;
#pragma unroll
        for (int jj = 0; jj < 8; jj += 4) {
            float4 a  = *(const float4*)(f0 + d2 + jj);
            float4 bb = *(const float4*)(f1 + d2 + jj);
            float4 cc = *(const float4*)(f2 + d2 + jj);
            o[jj]     = bf16rne(w0 * a.x + w1 * bb.x + w2 * cc.x);
            o[jj + 1] = bf16rne(w0 * a.y + w1 * bb.y + w2 * cc.y);
            o[jj + 2] = bf16rne(w0 * a.z + w1 * bb.z + w2 * cc.z);
            o[jj + 3] = bf16rne(w0 * a.w + w1 * bb.w + w2 * cc.w);
        }
        *(ush8*)(Xall + (mbase + r) * INC_ + 128 + d2) = o;
    }
}

// ---------------------------------------------------------------- GEMM1 (MFMA)
// D[row=c][col=m] = W1[c][k] * X[m][k]^T ; Y1[m][c] bf16, lane stores 4 consec c.
__global__ __launch_bounds__(256) void gemm1_kernel(
    const unsigned short* __restrict__ Xall,
    const unsigned short* __restrict__ Wb1,
    unsigned short* __restrict__ Y1)
{
    const int t  = blockIdx.z;
    const int m0 = blockIdx.x * 128;
    const int c0 = blockIdx.y * 128;
    const unsigned short* Aw = Wb1 + (size_t)t * (OC_ * INC_);
    const unsigned short* Bx = Xall + (size_t)t * M_ * INC_;

    __shared__ unsigned short Alds[128 * 64];
    __shared__ unsigned short Blds[128 * 64];

    const int tid  = threadIdx.x;
    const int lane = tid & 63;
    const int wid  = tid >> 6;
    const int wc   = wid & 1;
    const int wm   = wid >> 1;

    const int srow = tid >> 3;                       // staging row 0..31 (per issue)
    const int sk   = ((tid & 7) ^ (srow & 7)) * 8;   // xor-pre-swizzled source k

    f32x4 acc[4][4];
#pragma unroll
    for (int i = 0; i < 4; ++i)
#pragma unroll
        for (int j = 0; j < 4; ++j) acc[i][j] = f32x4{0.f, 0.f, 0.f, 0.f};

    const int arow = wc * 64 + (lane & 15);
    const int brow = wm * 64 + (lane & 15);
    const int kgrp = (lane >> 4) * 16;               // byte offset of k-group

    for (int kc = 0; kc < INC_; kc += 64) {
#pragma unroll
        for (int p = 0; p < 4; ++p) {
            int row = p * 32 + srow;
            gload16(Aw + (size_t)(c0 + row) * INC_ + kc + sk,
                    (char*)Alds + p * 4096 + wid * 1024);
            gload16(Bx + (size_t)(m0 + row) * INC_ + kc + sk,
                    (char*)Blds + p * 4096 + wid * 1024);
        }
        __syncthreads();
#pragma unroll
        for (int kk = 0; kk < 2; ++kk) {
            sh8 a[4], b[4];
#pragma unroll
            for (int f = 0; f < 4; ++f) {
                int ra = arow + f * 16;
                int rb = brow + f * 16;
                int oa = ra * 128 + ((kk * 64 + kgrp) ^ ((ra & 7) << 4));
                int ob = rb * 128 + ((kk * 64 + kgrp) ^ ((rb & 7) << 4));
                a[f] = *(const sh8*)((const char*)Alds + oa);
                b[f] = *(const sh8*)((const char*)Blds + ob);
            }
#pragma unroll
            for (int fc = 0; fc < 4; ++fc)
#pragma unroll
                for (int fm = 0; fm < 4; ++fm)
                    acc[fc][fm] = __builtin_amdgcn_mfma_f32_16x16x32_bf16(
                        a[fc], b[fm], acc[fc][fm], 0, 0, 0);
        }
        __syncthreads();
    }

    const int mloc = m0 + wm * 64 + (lane & 15);
    const int cloc = c0 + wc * 64 + (lane >> 4) * 4;
#pragma unroll
    for (int fm = 0; fm < 4; ++fm)
#pragma unroll
        for (int fc = 0; fc < 4; ++fc) {
            ush4 v;
#pragma unroll
            for (int r = 0; r < 4; ++r) v[r] = bf16rne(acc[fc][fm][r]);
            *(ush4*)(Y1 + ((size_t)t * M_ + mloc + fm * 16) * OC_ + cloc + fc * 16) = v;
        }
}

// ---------------------------------------------------------------- stats of Y1
__global__ __launch_bounds__(256) void stats1_kernel(
    const unsigned short* __restrict__ Y1,
    float* __restrict__ psum, float* __restrict__ psq)
{
    const int t = blockIdx.y, blk = blockIdx.x;
    const int tid = threadIdx.x;
    const int c8 = tid & 31, msub = tid >> 5;
    __shared__ float ps[8][256], pq[8][256];
    float s[8], q[8];
#pragma unroll
    for (int j = 0; j < 8; ++j) { s[j] = 0.f; q[j] = 0.f; }
    const unsigned short* base = Y1 + (size_t)t * M_ * OC_ + (size_t)blk * 512 * OC_ + c8 * 8;
    for (int i = 0; i < 64; ++i) {
        int m = i * 8 + msub;
        ush8 v = *(const ush8*)(base + (size_t)m * OC_);
#pragma unroll
        for (int j = 0; j < 8; ++j) { float f = bf2f(v[j]); s[j] += f; q[j] += f * f; }
    }
#pragma unroll
    for (int j = 0; j < 8; ++j) { ps[msub][c8 * 8 + j] = s[j]; pq[msub][c8 * 8 + j] = q[j]; }
    __syncthreads();
    float ss_ = 0.f, qq_ = 0.f;
#pragma unroll
    for (int r = 0; r < 8; ++r) { ss_ += ps[r][tid]; qq_ += pq[r][tid]; }
    psum[((size_t)t * 64 + blk) * 256 + tid] = ss_;
    psq [((size_t)t * 64 + blk) * 256 + tid] = qq_;
}

__global__ __launch_bounds__(256) void reduce1_kernel(
    const float* __restrict__ psum, const float* __restrict__ psq,
    const float* __restrict__ gp, const float* __restrict__ bep,
    const float* __restrict__ gc, const float* __restrict__ bec,
    float* __restrict__ ss)
{
    int t = blockIdx.x, c = threadIdx.x;
    float s = 0.f, q = 0.f;
    for (int i = 0; i < 64; ++i) {
        s += psum[((size_t)t * 64 + i) * 256 + c];
        q += psq [((size_t)t * 64 + i) * 256 + c];
    }
    float mean = s * (1.f / (float)M_);
    float var  = q * (1.f / (float)M_) - mean * mean;
    float inv  = rsqrtf(var + 1e-5f);
    float g = (t ? gc : gp)[c], be = (t ? bec : bep)[c];
    float sc = g * inv;
    ss[t * 256 + c]       = sc;
    ss[512 + t * 256 + c] = be - mean * sc;
}

// ---------------------------------------------------------------- GEMM2 (MFMA)
// D[row=o][col=m] = W2[o][k] * relu(bn(Y1))[m][k]^T ; raw y2 -> out[t][b][o][n]
__global__ __launch_bounds__(256) void gemm2_kernel(
    const unsigned short* __restrict__ Y1,
    const unsigned short* __restrict__ Wb2,
    const float* __restrict__ ss,
    float* __restrict__ out)
{
    const int t   = blockIdx.z;
    const int m0g = blockIdx.x * 128;
    const int o0  = blockIdx.y * 128;
    const int b   = m0g >> 12;
    const int n0  = m0g & (N_ - 1);
    const unsigned short* Aw = Wb2 + (size_t)t * (OC_ * OC_);
    const unsigned short* By = Y1 + (size_t)t * M_ * OC_;

    __shared__ unsigned short Alds[128 * 64];
    __shared__ unsigned short Blds[128 * 64];
    __shared__ float Slds[256], Hlds[256];

    const int tid  = threadIdx.x;
    const int lane = tid & 63;
    const int wid  = tid >> 6;
    const int wc   = wid & 1;
    const int wm   = wid >> 1;

    Slds[tid] = ss[t * 256 + tid];
    Hlds[tid] = ss[512 + t * 256 + tid];
    __syncthreads();

    const int srow = tid >> 3;
    const int sk   = ((tid & 7) ^ (srow & 7)) * 8;

    f32x4 acc[4][4];
#pragma unroll
    for (int i = 0; i < 4; ++i)
#pragma unroll
        for (int j = 0; j < 4; ++j) acc[i][j] = f32x4{0.f, 0.f, 0.f, 0.f};

    const int arow = wc * 64 + (lane & 15);
    const int brow = wm * 64 + (lane & 15);
    const int kgrp = (lane >> 4) * 16;

    for (int kc = 0; kc < OC_; kc += 64) {
        // A: weights via global_load_lds (pre-swizzled source)
#pragma unroll
        for (int p = 0; p < 4; ++p) {
            int row = p * 32 + srow;
            gload16(Aw + (size_t)(o0 + row) * OC_ + kc + sk,
                    (char*)Alds + p * 4096 + wid * 1024);
        }
        // B: reg-staged bn+relu(Y1), swizzled ds_write_b128
#pragma unroll
        for (int p = 0; p < 4; ++p) {
            int qn  = p * 256 + tid;
            int row = qn >> 3;
            int k8  = (qn & 7) * 8;
            ush8 yv = *(const ush8*)(By + (size_t)(m0g + row) * OC_ + kc + k8);
            ush8 ov;
#pragma unroll
            for (int j = 0; j < 8; ++j) {
                float y = bf2f(yv[j]);
                float x = fmaxf(0.f, fmaf(y, Slds[kc + k8 + j], Hlds[kc + k8 + j]));
                ov[j] = bf16rne(x);
            }
            int phys = row * 128 + ((k8 * 2) ^ ((row & 7) << 4));
            *(ush8*)((char*)Blds + phys) = ov;
        }
        __syncthreads();
#pragma unroll
        for (int kk = 0; kk < 2; ++kk) {
            sh8 a[4], bfr[4];
#pragma unroll
            for (int f = 0; f < 4; ++f) {
                int ra = arow + f * 16;
                int rb = brow + f * 16;
                int oa = ra * 128 + ((kk * 64 + kgrp) ^ ((ra & 7) << 4));
                int ob = rb * 128 + ((kk * 64 + kgrp) ^ ((rb & 7) << 4));
                a[f]   = *(const sh8*)((const char*)Alds + oa);
                bfr[f] = *(const sh8*)((const char*)Blds + ob);
            }
#pragma unroll
            for (int fc = 0; fc < 4; ++fc)
#pragma unroll
                for (int fm = 0; fm < 4; ++fm)
                    acc[fc][fm] = __builtin_amdgcn_mfma_f32_16x16x32_bf16(
                        a[fc], bfr[fm], acc[fc][fm], 0, 0, 0);
        }
        __syncthreads();
    }

    const int nloc = n0 + wm * 64 + (lane & 15);
    const int oloc = o0 + wc * 64 + (lane >> 4) * 4;
    float* ob = out + ((size_t)t * B_ + b) * ((size_t)OC_ * N_);
#pragma unroll
    for (int fc = 0; fc < 4; ++fc)
#pragma unroll
        for (int fm = 0; fm < 4; ++fm)
#pragma unroll
            for (int r = 0; r < 4; ++r)
                ob[(size_t)(oloc + fc * 16 + r) * N_ + nloc + fm * 16] = acc[fc][fm][r];
}

// ---------------------------------------------------------------- stats of y2
__global__ __launch_bounds__(256) void stats2_kernel(
    const float* __restrict__ out,
    const float* __restrict__ gp, const float* __restrict__ bep,
    const float* __restrict__ gc, const float* __restrict__ bec,
    float* __restrict__ ss)
{
    const int t = blockIdx.y, o = blockIdx.x;
    const int tid = threadIdx.x;
    float s = 0.f, q = 0.f;
    for (int b = 0; b < B_; ++b) {
        const float* p = out + (((size_t)t * B_ + b) * OC_ + o) * N_;
#pragma unroll
        for (int k = 0; k < 4; ++k) {
            float4 v = *(const float4*)(p + (tid + k * 256) * 4);
            s += v.x + v.y + v.z + v.w;
            q += v.x * v.x + v.y * v.y + v.z * v.z + v.w * v.w;
        }
    }
#pragma unroll
    for (int off = 32; off; off >>= 1) {
        s += __shfl_down(s, off);
        q += __shfl_down(q, off);
    }
    __shared__ float rs[4], rq[4];
    if ((tid & 63) == 0) { rs[tid >> 6] = s; rq[tid >> 6] = q; }
    __syncthreads();
    if (tid == 0) {
        s = rs[0] + rs[1] + rs[2] + rs[3];
        q = rq[0] + rq[1] + rq[2] + rq[3];
        float mean = s * (1.f / (float)M_);
        float var  = q * (1.f / (float)M_) - mean * mean;
        float inv  = rsqrtf(var + 1e-5f);
        float g = (t ? gc : gp)[o], be = (t ? bec : bep)[o];
        float sc = g * inv;
        ss[1024 + t * 256 + o] = sc;
        ss[1536 + t * 256 + o] = be - mean * sc;
    }
}

// ---------------------------------------------------------------- final BN+ReLU
__global__ __launch_bounds__(256) void bnfinal_kernel(
    float* __restrict__ out, const float* __restrict__ ss)
{
    const int total4 = 2 * B_ * OC_ * N_ / 4;
    for (int i4 = blockIdx.x * blockDim.x + threadIdx.x; i4 < total4;
         i4 += gridDim.x * blockDim.x) {
        size_t i = (size_t)i4 * 4;
        int o = (int)((i >> 12) & 255);
        int t = (int)(i >> 23);
        float sc = ss[1024 + t * OC_ + o];
        float sh = ss[1536 + t * OC_ + o];
        float4 v = ((float4*)out)[i4];
        v.x = fmaxf(0.f, fmaf(v.x, sc, sh));
        v.y = fmaxf(0.f, fmaf(v.y, sc, sh));
        v.z = fmaxf(0.f, fmaf(v.z, sc, sh));
        v.w = fmaxf(0.f, fmaf(v.w, sc, sh));
        ((float4*)out)[i4] = v;
    }
}

// ---------------------------------------------------------------- launch
extern "C" void kernel_launch(void* const* d_in, const int* in_sizes, int n_in,
                              void* d_out, int out_size, void* d_ws, size_t ws_size,
                              hipStream_t stream)
{
    const float* xyz1    = (const float*)d_in[0];
    const float* xyz2    = (const float*)d_in[1];
    const float* points1 = (const float*)d_in[2];
    const float* points2 = (const float*)d_in[3];
    const float* colors1 = (const float*)d_in[4];
    const float* colors2 = (const float*)d_in[5];
    const float* Wp1  = (const float*)d_in[6];
    const float* gp1  = (const float*)d_in[8];
    const float* bep1 = (const float*)d_in[9];
    const float* Wc1  = (const float*)d_in[10];
    const float* gc1  = (const float*)d_in[12];
    const float* bec1 = (const float*)d_in[13];
    const float* Wp2  = (const float*)d_in[14];
    const float* gp2  = (const float*)d_in[16];
    const float* bep2 = (const float*)d_in[17];
    const float* Wc2  = (const float*)d_in[18];
    const float* gc2  = (const float*)d_in[20];
    const float* bec2 = (const float*)d_in[21];
    // biases (d_in[7,11,15,19]) unused: constant channel shift cancels in BN.

    char* ws = (char*)d_ws;
    unsigned short* Xall = (unsigned short*)(ws + 0);
    unsigned short* Wb1  = (unsigned short*)(ws + 50331648);
    unsigned short* Wb2  = (unsigned short*)(ws + 50724864);
    float* ssb  = (float*)(ws + 50987008);
    float* psum = (float*)(ws + 50995200);
    float* psq  = (float*)(ws + 51126272);
    float* p2t  = (float*)(ws + 51257344);
    float* c2t  = (float*)(ws + 59645952);
    int*   idxw = (int*)  (ws + 68034560);
    float* wgtw = (float*)(ws + 68427776);
    unsigned short* Y1 = (unsigned short*)(ws + 51257344); // overlays transients
    float* out = (float*)d_out;

    dim3 tb(32, 8);
    transpose_kernel<<<dim3(32, 8, 8), tb, 0, stream>>>(points2, p2t, 256, 1024);
    transpose_kernel<<<dim3(32, 8, 8), tb, 0, stream>>>(colors2, c2t, 256, 1024);
    convw_kernel<<<320, 256, 0, stream>>>(Wp1, Wc1, Wp2, Wc2, Wb1, Wb2);
    top3_kernel<<<dim3(16, 8), 256, 0, stream>>>(xyz1, xyz2, idxw, wgtw);
    buildx_kernel<<<dim3(64, 8, 2), 256, 0, stream>>>(points1, colors1, p2t, c2t,
                                                      idxw, wgtw, Xall);
    gemm1_kernel<<<dim3(256, 2, 2), 256, 0, stream>>>(Xall, Wb1, Y1);
    stats1_kernel<<<dim3(64, 2), 256, 0, stream>>>(Y1, psum, psq);
    reduce1_kernel<<<2, 256, 0, stream>>>(psum, psq, gp1, bep1, gc1, bec1, ssb);
    gemm2_kernel<<<dim3(256, 2, 2), 256, 0, stream>>>(Y1, Wb2, ssb, out);
    stats2_kernel<<<dim3(256, 2), 256, 0, stream>>>(out, gp2, bep2, gc2, bec2, ssb);
    bnfinal_kernel<<<4096, 256, 0, stream>>>(out, ssb);
}

// Round 3
// 194.030 us; speedup vs baseline: 2.6270x; 1.3304x over previous
//
#include <hip/hip_runtime.h>
#include <cstdint>
#include <cstddef>

// PointNet++ FP, bf16-MFMA pipeline, parallel top3 + fused BN stats.
// B=8, N=4096, S=1024, D1=128, D2=256, IN_C=384, MLP=[256,256], BN training.
//
//  transpose p2t/c2t -> [B][S][D2]
//  convw: W* -> bf16 [o][k]
//  top3:  8 lanes/query, branchless scan + shfl_xor lexicographic merge
//  buildx: Xall[t][m][384] bf16 = [points1^T | interp]
//  gemm1: MFMA, Y1[m][c] bf16 + fused channel sum/sumsq partials (fp32 acc)
//  reduce(0): mean/var -> folded scale/shift (bias skipped: cancels in BN)
//  gemm2: stage relu(bn(Y1)), raw y2 fp32 -> d_out [t][b][o][n] + fused partials
//  reduce(1024), bnfinal: in-place relu(y2*sc+sh)
//
// ws layout (bytes), max 85,598,208:
//   Xall 0 | Wb1 50331648 | Wb2 50724864 | ss 50987008 | psum 50995200
//   psq 51519488 | transients@52043776: p2t,c2t(+8.4MB ea),idx,wgt
//   Y1 overlays transients @52043776 (33554432)

#define B_   8
#define N_   4096
#define S_   1024
#define D1_  128
#define D2_  256
#define INC_ 384
#define OC_  256
#define M_   (B_ * N_)

typedef __attribute__((ext_vector_type(8))) short sh8;
typedef __attribute__((ext_vector_type(4))) float f32x4;
typedef __attribute__((ext_vector_type(4))) unsigned short ush4;
typedef __attribute__((ext_vector_type(8))) unsigned short ush8;

__device__ __forceinline__ unsigned short bf16rne(float f) {
    union { float f; unsigned u; } v; v.f = f;
    return (unsigned short)((v.u + 0x7FFFu + ((v.u >> 16) & 1u)) >> 16);
}
__device__ __forceinline__ float bf2f(unsigned short h) {
    union { unsigned u; float f; } v; v.u = ((unsigned)h) << 16;
    return v.f;
}
__device__ __forceinline__ void gload16(const void* gsrc, void* lds) {
    __builtin_amdgcn_global_load_lds(
        (const __attribute__((address_space(1))) void*)gsrc,
        (__attribute__((address_space(3))) void*)lds, 16, 0, 0);
}

// ---------------------------------------------------------------- transpose
__global__ __launch_bounds__(256) void transpose_kernel(
    const float* __restrict__ src, float* __restrict__ dst, int R, int C)
{
    __shared__ float tile[32][33];
    const float* s = src + (size_t)blockIdx.z * R * C;
    float*       d = dst + (size_t)blockIdx.z * R * C;
    int c = blockIdx.x * 32 + threadIdx.x;
#pragma unroll
    for (int i = 0; i < 4; ++i) {
        int r = blockIdx.y * 32 + threadIdx.y + i * 8;
        tile[threadIdx.y + i * 8][threadIdx.x] = s[(size_t)r * C + c];
    }
    __syncthreads();
    int r2 = blockIdx.y * 32 + threadIdx.x;
#pragma unroll
    for (int i = 0; i < 4; ++i) {
        int c2 = blockIdx.x * 32 + threadIdx.y + i * 8;
        d[(size_t)c2 * R + r2] = tile[threadIdx.x][threadIdx.y + i * 8];
    }
}

// ---------------------------------------------------------------- W -> bf16
__global__ __launch_bounds__(256) void convw_kernel(
    const float* __restrict__ Wp1, const float* __restrict__ Wc1,
    const float* __restrict__ Wp2, const float* __restrict__ Wc2,
    unsigned short* __restrict__ Wb1, unsigned short* __restrict__ Wb2)
{
    int e = (blockIdx.x * 256 + threadIdx.x) * 4;
    const float* src; unsigned short* dst; int off;
    if (e < 98304)       { src = Wp1; dst = Wb1;          off = e; }
    else if (e < 196608) { src = Wc1; dst = Wb1 + 98304;  off = e - 98304; }
    else if (e < 262144) { src = Wp2; dst = Wb2;          off = e - 196608; }
    else                 { src = Wc2; dst = Wb2 + 65536;  off = e - 262144; }
    float4 v = *(const float4*)(src + off);
    ush4 o; o[0] = bf16rne(v.x); o[1] = bf16rne(v.y); o[2] = bf16rne(v.z); o[3] = bf16rne(v.w);
    *(ush4*)(dst + off) = o;
}

// ---------------------------------------------------------------- top-3 NN
// 8 lanes per query, 128 interleaved candidates each, butterfly merge.
#define INS(pd, pi) { \
    bool l0 = (pd < d0) || (pd == d0 && pi < i0); \
    bool l1 = (pd < d1) || (pd == d1 && pi < i1); \
    bool l2 = (pd < d2) || (pd == d2 && pi < i2); \
    d2 = l1 ? d1 : (l2 ? pd : d2);  i2 = l1 ? i1 : (l2 ? pi : i2); \
    d1 = l0 ? d0 : (l1 ? pd : d1);  i1 = l0 ? i0 : (l1 ? pi : i1); \
    d0 = l0 ? pd : d0;              i0 = l0 ? pi : i0; \
}

__global__ __launch_bounds__(256) void top3_kernel(
    const float* __restrict__ xyz1, const float* __restrict__ xyz2,
    int* __restrict__ idxo, float* __restrict__ wo)
{
    __shared__ float4 sc[S_];
    const int b = blockIdx.y;
    const int tid = threadIdx.x;
    const float* x2 = xyz2 + (size_t)b * 3 * S_;
    for (int s = tid; s < S_; s += 256) {
        float xs = x2[s], ys = x2[S_ + s], zs = x2[2 * S_ + s];
        sc[s] = make_float4(xs, ys, zs, xs * xs + ys * ys + zs * zs);
    }
    __syncthreads();
    const int q = blockIdx.x * 32 + (tid >> 3);
    const int sub = tid & 7;
    const float* x1 = xyz1 + (size_t)b * 3 * N_;
    const float xq = x1[q], yq = x1[N_ + q], zq = x1[2 * N_ + q];
    const float n1 = xq * xq + yq * yq + zq * zq;
    float d0 = 3.4e38f, d1 = 3.4e38f, d2 = 3.4e38f;
    int i0 = 0, i1 = 0, i2 = 0;
#pragma unroll 4
    for (int j = 0; j < 128; ++j) {
        int s = j * 8 + sub;
        float4 v = sc[s];
        float dot = xq * v.x + yq * v.y + zq * v.z;
        float d = (n1 - 2.0f * dot) + v.w;
        // strict < : ascending-index scan keeps earlier index on ties
        bool c0 = d < d0, c1 = d < d1, c2 = d < d2;
        d2 = c1 ? d1 : (c2 ? d : d2); i2 = c1 ? i1 : (c2 ? s : i2);
        d1 = c0 ? d0 : (c1 ? d : d1); i1 = c0 ? i0 : (c1 ? s : i1);
        d0 = c0 ? d : d0;             i0 = c0 ? s : i0;
    }
#pragma unroll
    for (int off = 1; off < 8; off <<= 1) {
        float pd0 = __shfl_xor(d0, off), pd1 = __shfl_xor(d1, off), pd2 = __shfl_xor(d2, off);
        int   pi0 = __shfl_xor(i0, off), pi1 = __shfl_xor(i1, off), pi2 = __shfl_xor(i2, off);
        INS(pd0, pi0) INS(pd1, pi1) INS(pd2, pi2)
    }
    if (sub == 0) {
        float r0 = 1.f / (d0 + 1e-8f);
        float r1 = 1.f / (d1 + 1e-8f);
        float r2 = 1.f / (d2 + 1e-8f);
        float rs = r0 + r1 + r2;
        int base = (b * N_ + q) * 3;
        idxo[base] = i0; idxo[base + 1] = i1; idxo[base + 2] = i2;
        wo[base] = r0 / rs; wo[base + 1] = r1 / rs; wo[base + 2] = r2 / rs;
    }
}

// ---------------------------------------------------------------- build X (bf16)
__global__ __launch_bounds__(256) void buildx_kernel(
    const float* __restrict__ points1, const float* __restrict__ colors1,
    const float* __restrict__ p2t, const float* __restrict__ c2t,
    const int* __restrict__ idxw, const float* __restrict__ wgtw,
    unsigned short* __restrict__ Xall)
{
    const int t = blockIdx.z, b = blockIdx.y, n0 = blockIdx.x * 64;
    const float* x1  = t ? colors1 : points1;
    const float* f2t = t ? c2t : p2t;
    const int tid = threadIdx.x;
    __shared__ float tileA[64][132];

#pragma unroll
    for (int it = 0; it < 8; ++it) {
        int fl4 = it * 256 + tid;
        int d = fl4 >> 4, nl = (fl4 & 15) * 4;
        float4 v = *(const float4*)(x1 + ((size_t)b * D1_ + d) * N_ + n0 + nl);
        tileA[nl][d] = v.x; tileA[nl + 1][d] = v.y; tileA[nl + 2][d] = v.z; tileA[nl + 3][d] = v.w;
    }
    __syncthreads();
    size_t mbase = (size_t)t * M_ + (size_t)b * N_ + n0;
#pragma unroll
    for (int it = 0; it < 4; ++it) {
        int e8 = it * 256 + tid;
        int r = e8 >> 4, dc = (e8 & 15) * 8;
        ush8 o;
#pragma unroll
        for (int j = 0; j < 8; ++j) o[j] = bf16rne(tileA[r][dc + j]);
        *(ush8*)(Xall + (mbase + r) * INC_ + dc) = o;
    }

    const int r = tid >> 2, qq = tid & 3;
    const int nb = (b * N_ + n0 + r) * 3;
    int i0 = idxw[nb], i1 = idxw[nb + 1], i2 = idxw[nb + 2];
    float w0 = wgtw[nb], w1 = wgtw[nb + 1], w2 = wgtw[nb + 2];
    const float* f0 = f2t + ((size_t)b * S_ + i0) * D2_;
    const float* f1 = f2t + ((size_t)b * S_ + i1) * D2_;
    const float* f2 = f2t + ((size_t)b * S_ + i2) * D2_;
#pragma unroll
    for (int c8 = 0; c8 < 8; ++c8) {
        int d2 = qq * 64 + c8 * 8;
        ush8 o;
#pragma unroll
        for (int jj = 0; jj < 8; jj += 4) {
            float4 a  = *(const float4*)(f0 + d2 + jj);
            float4 bb = *(const float4*)(f1 + d2 + jj);
            float4 cc = *(const float4*)(f2 + d2 + jj);
            o[jj]     = bf16rne(w0 * a.x + w1 * bb.x + w2 * cc.x);
            o[jj + 1] = bf16rne(w0 * a.y + w1 * bb.y + w2 * cc.y);
            o[jj + 2] = bf16rne(w0 * a.z + w1 * bb.z + w2 * cc.z);
            o[jj + 3] = bf16rne(w0 * a.w + w1 * bb.w + w2 * cc.w);
        }
        *(ush8*)(Xall + (mbase + r) * INC_ + 128 + d2) = o;
    }
}

// ---------------------------------------------------------------- GEMM1 (MFMA)
// D[row=c][col=m]; Y1[m][c] bf16; fused fp32 stats partials.
__global__ __launch_bounds__(256) void gemm1_kernel(
    const unsigned short* __restrict__ Xall,
    const unsigned short* __restrict__ Wb1,
    unsigned short* __restrict__ Y1,
    float* __restrict__ psum, float* __restrict__ psq)
{
    const int t  = blockIdx.z;
    const int m0 = blockIdx.x * 128;
    const int c0 = blockIdx.y * 128;
    const unsigned short* Aw = Wb1 + (size_t)t * (OC_ * INC_);
    const unsigned short* Bx = Xall + (size_t)t * M_ * INC_;

    __shared__ __align__(16) char smem[33792];
    unsigned short* Alds = (unsigned short*)smem;
    unsigned short* Blds = (unsigned short*)(smem + 16384);

    const int tid  = threadIdx.x;
    const int lane = tid & 63;
    const int wid  = tid >> 6;
    const int wc   = wid & 1;
    const int wm   = wid >> 1;

    const int srow = tid >> 3;
    const int sk   = ((tid & 7) ^ (srow & 7)) * 8;

    f32x4 acc[4][4];
#pragma unroll
    for (int i = 0; i < 4; ++i)
#pragma unroll
        for (int j = 0; j < 4; ++j) acc[i][j] = f32x4{0.f, 0.f, 0.f, 0.f};

    const int arow = wc * 64 + (lane & 15);
    const int brow = wm * 64 + (lane & 15);
    const int kgrp = (lane >> 4) * 16;

    for (int kc = 0; kc < INC_; kc += 64) {
#pragma unroll
        for (int p = 0; p < 4; ++p) {
            int row = p * 32 + srow;
            gload16(Aw + (size_t)(c0 + row) * INC_ + kc + sk,
                    (char*)Alds + p * 4096 + wid * 1024);
            gload16(Bx + (size_t)(m0 + row) * INC_ + kc + sk,
                    (char*)Blds + p * 4096 + wid * 1024);
        }
        __syncthreads();
#pragma unroll
        for (int kk = 0; kk < 2; ++kk) {
            sh8 a[4], b[4];
#pragma unroll
            for (int f = 0; f < 4; ++f) {
                int ra = arow + f * 16;
                int rb = brow + f * 16;
                int oa = ra * 128 + ((kk * 64 + kgrp) ^ ((ra & 7) << 4));
                int ob = rb * 128 + ((kk * 64 + kgrp) ^ ((rb & 7) << 4));
                a[f] = *(const sh8*)((const char*)Alds + oa);
                b[f] = *(const sh8*)((const char*)Blds + ob);
            }
#pragma unroll
            for (int fc = 0; fc < 4; ++fc)
#pragma unroll
                for (int fm = 0; fm < 4; ++fm)
                    acc[fc][fm] = __builtin_amdgcn_mfma_f32_16x16x32_bf16(
                        a[fc], b[fm], acc[fc][fm], 0, 0, 0);
        }
        __syncthreads();
    }

    const int mloc = m0 + wm * 64 + (lane & 15);
    const int cloc = c0 + wc * 64 + (lane >> 4) * 4;
#pragma unroll
    for (int fm = 0; fm < 4; ++fm)
#pragma unroll
        for (int fc = 0; fc < 4; ++fc) {
            ush4 v;
#pragma unroll
            for (int r = 0; r < 4; ++r) v[r] = bf16rne(acc[fc][fm][r]);
            *(ush4*)(Y1 + ((size_t)t * M_ + mloc + fm * 16) * OC_ + cloc + fc * 16) = v;
        }

    // fused stats partials (deterministic): LDS [contrib 32][ch 128+pad]
    float* sArr = (float*)smem;          // 32*132 floats
    float* qArr = sArr + 32 * 132;
    const int contrib = wm * 16 + (lane & 15);
#pragma unroll
    for (int fc = 0; fc < 4; ++fc) {
        f32x4 s4, q4;
#pragma unroll
        for (int r = 0; r < 4; ++r) {
            float s = 0.f, qv = 0.f;
#pragma unroll
            for (int fm = 0; fm < 4; ++fm) { float v = acc[fc][fm][r]; s += v; qv += v * v; }
            s4[r] = s; q4[r] = qv;
        }
        int chL = wc * 64 + (lane >> 4) * 4 + fc * 16;
        *(f32x4*)&sArr[contrib * 132 + chL] = s4;
        *(f32x4*)&qArr[contrib * 132 + chL] = q4;
    }
    __syncthreads();
    {
        int which = tid >> 7, ch = tid & 127;
        const float* a = which ? qArr : sArr;
        float r = 0.f;
#pragma unroll
        for (int k = 0; k < 32; ++k) {
            int cb = (k + (ch >> 2)) & 31;
            r += a[cb * 132 + ch];
        }
        float* dst = which ? psq : psum;
        dst[((size_t)t * 256 + blockIdx.x) * 256 + blockIdx.y * 128 + ch] = r;
    }
}

// ---------------------------------------------------------------- stats reduce
__global__ __launch_bounds__(256) void reduce_kernel(
    const float* __restrict__ psum, const float* __restrict__ psq,
    const float* __restrict__ gp, const float* __restrict__ bep,
    const float* __restrict__ gc, const float* __restrict__ bec,
    float* __restrict__ ss, int layerOff)
{
    const int t = blockIdx.x, cs = blockIdx.y;
    const int tid = threadIdx.x;
    const int cl = tid & 63, grp = tid >> 6;
    const int c = cs * 64 + cl;
    float s = 0.f, q = 0.f;
    for (int k = grp; k < 256; k += 4) {
        s += psum[((size_t)t * 256 + k) * 256 + c];
        q += psq [((size_t)t * 256 + k) * 256 + c];
    }
    __shared__ float ls[4][64], lq[4][64];
    ls[grp][cl] = s; lq[grp][cl] = q;
    __syncthreads();
    if (tid < 64) {
        s = ls[0][cl] + ls[1][cl] + ls[2][cl] + ls[3][cl];
        q = lq[0][cl] + lq[1][cl] + lq[2][cl] + lq[3][cl];
        float mean = s * (1.f / (float)M_);
        float var  = q * (1.f / (float)M_) - mean * mean;
        float inv  = rsqrtf(var + 1e-5f);
        float g = (t ? gc : gp)[c], be = (t ? bec : bep)[c];
        float sc = g * inv;
        ss[layerOff + t * 256 + c]       = sc;
        ss[layerOff + 512 + t * 256 + c] = be - mean * sc;
    }
}

// ---------------------------------------------------------------- GEMM2 (MFMA)
__global__ __launch_bounds__(256) void gemm2_kernel(
    const unsigned short* __restrict__ Y1,
    const unsigned short* __restrict__ Wb2,
    const float* __restrict__ ss,
    float* __restrict__ out,
    float* __restrict__ psum, float* __restrict__ psq)
{
    const int t   = blockIdx.z;
    const int m0g = blockIdx.x * 128;
    const int o0  = blockIdx.y * 128;
    const int b   = m0g >> 12;
    const int n0  = m0g & (N_ - 1);
    const unsigned short* Aw = Wb2 + (size_t)t * (OC_ * OC_);
    const unsigned short* By = Y1 + (size_t)t * M_ * OC_;

    __shared__ __align__(16) char smem[33792];
    unsigned short* Alds = (unsigned short*)smem;
    unsigned short* Blds = (unsigned short*)(smem + 16384);
    __shared__ float Slds[256], Hlds[256];

    const int tid  = threadIdx.x;
    const int lane = tid & 63;
    const int wid  = tid >> 6;
    const int wc   = wid & 1;
    const int wm   = wid >> 1;

    Slds[tid] = ss[t * 256 + tid];
    Hlds[tid] = ss[512 + t * 256 + tid];
    __syncthreads();

    const int srow = tid >> 3;
    const int sk   = ((tid & 7) ^ (srow & 7)) * 8;

    f32x4 acc[4][4];
#pragma unroll
    for (int i = 0; i < 4; ++i)
#pragma unroll
        for (int j = 0; j < 4; ++j) acc[i][j] = f32x4{0.f, 0.f, 0.f, 0.f};

    const int arow = wc * 64 + (lane & 15);
    const int brow = wm * 64 + (lane & 15);
    const int kgrp = (lane >> 4) * 16;

    for (int kc = 0; kc < OC_; kc += 64) {
#pragma unroll
        for (int p = 0; p < 4; ++p) {
            int row = p * 32 + srow;
            gload16(Aw + (size_t)(o0 + row) * OC_ + kc + sk,
                    (char*)Alds + p * 4096 + wid * 1024);
        }
#pragma unroll
        for (int p = 0; p < 4; ++p) {
            int qn  = p * 256 + tid;
            int row = qn >> 3;
            int k8  = (qn & 7) * 8;
            ush8 yv = *(const ush8*)(By + (size_t)(m0g + row) * OC_ + kc + k8);
            ush8 ov;
#pragma unroll
            for (int j = 0; j < 8; ++j) {
                float y = bf2f(yv[j]);
                float x = fmaxf(0.f, fmaf(y, Slds[kc + k8 + j], Hlds[kc + k8 + j]));
                ov[j] = bf16rne(x);
            }
            int phys = row * 128 + ((k8 * 2) ^ ((row & 7) << 4));
            *(ush8*)((char*)Blds + phys) = ov;
        }
        __syncthreads();
#pragma unroll
        for (int kk = 0; kk < 2; ++kk) {
            sh8 a[4], bfr[4];
#pragma unroll
            for (int f = 0; f < 4; ++f) {
                int ra = arow + f * 16;
                int rb = brow + f * 16;
                int oa = ra * 128 + ((kk * 64 + kgrp) ^ ((ra & 7) << 4));
                int ob = rb * 128 + ((kk * 64 + kgrp) ^ ((rb & 7) << 4));
                a[f]   = *(const sh8*)((const char*)Alds + oa);
                bfr[f] = *(const sh8*)((const char*)Blds + ob);
            }
#pragma unroll
            for (int fc = 0; fc < 4; ++fc)
#pragma unroll
                for (int fm = 0; fm < 4; ++fm)
                    acc[fc][fm] = __builtin_amdgcn_mfma_f32_16x16x32_bf16(
                        a[fc], bfr[fm], acc[fc][fm], 0, 0, 0);
        }
        __syncthreads();
    }

    const int nloc = n0 + wm * 64 + (lane & 15);
    const int oloc = o0 + wc * 64 + (lane >> 4) * 4;
    float* ob = out + ((size_t)t * B_ + b) * ((size_t)OC_ * N_);
#pragma unroll
    for (int fc = 0; fc < 4; ++fc)
#pragma unroll
        for (int fm = 0; fm < 4; ++fm)
#pragma unroll
            for (int r = 0; r < 4; ++r)
                ob[(size_t)(oloc + fc * 16 + r) * N_ + nloc + fm * 16] = acc[fc][fm][r];

    // fused stats partials
    float* sArr = (float*)smem;
    float* qArr = sArr + 32 * 132;
    const int contrib = wm * 16 + (lane & 15);
#pragma unroll
    for (int fc = 0; fc < 4; ++fc) {
        f32x4 s4, q4;
#pragma unroll
        for (int r = 0; r < 4; ++r) {
            float s = 0.f, qv = 0.f;
#pragma unroll
            for (int fm = 0; fm < 4; ++fm) { float v = acc[fc][fm][r]; s += v; qv += v * v; }
            s4[r] = s; q4[r] = qv;
        }
        int chL = wc * 64 + (lane >> 4) * 4 + fc * 16;
        *(f32x4*)&sArr[contrib * 132 + chL] = s4;
        *(f32x4*)&qArr[contrib * 132 + chL] = q4;
    }
    __syncthreads();
    {
        int which = tid >> 7, ch = tid & 127;
        const float* a = which ? qArr : sArr;
        float r = 0.f;
#pragma unroll
        for (int k = 0; k < 32; ++k) {
            int cb = (k + (ch >> 2)) & 31;
            r += a[cb * 132 + ch];
        }
        float* dst = which ? psq : psum;
        dst[((size_t)t * 256 + blockIdx.x) * 256 + blockIdx.y * 128 + ch] = r;
    }
}

// ---------------------------------------------------------------- final BN+ReLU
__global__ __launch_bounds__(256) void bnfinal_kernel(
    float* __restrict__ out, const float* __restrict__ ss)
{
    const int total4 = 2 * B_ * OC_ * N_ / 4;
    for (int i4 = blockIdx.x * blockDim.x + threadIdx.x; i4 < total4;
         i4 += gridDim.x * blockDim.x) {
        size_t i = (size_t)i4 * 4;
        int o = (int)((i >> 12) & 255);
        int t = (int)(i >> 23);
        float sc = ss[1024 + t * OC_ + o];
        float sh = ss[1536 + t * OC_ + o];
        float4 v = ((float4*)out)[i4];
        v.x = fmaxf(0.f, fmaf(v.x, sc, sh));
        v.y = fmaxf(0.f, fmaf(v.y, sc, sh));
        v.z = fmaxf(0.f, fmaf(v.z, sc, sh));
        v.w = fmaxf(0.f, fmaf(v.w, sc, sh));
        ((float4*)out)[i4] = v;
    }
}

// ---------------------------------------------------------------- launch
extern "C" void kernel_launch(void* const* d_in, const int* in_sizes, int n_in,
                              void* d_out, int out_size, void* d_ws, size_t ws_size,
                              hipStream_t stream)
{
    const float* xyz1    = (const float*)d_in[0];
    const float* xyz2    = (const float*)d_in[1];
    const float* points1 = (const float*)d_in[2];
    const float* points2 = (const float*)d_in[3];
    const float* colors1 = (const float*)d_in[4];
    const float* colors2 = (const float*)d_in[5];
    const float* Wp1  = (const float*)d_in[6];
    const float* gp1  = (const float*)d_in[8];
    const float* bep1 = (const float*)d_in[9];
    const float* Wc1  = (const float*)d_in[10];
    const float* gc1  = (const float*)d_in[12];
    const float* bec1 = (const float*)d_in[13];
    const float* Wp2  = (const float*)d_in[14];
    const float* gp2  = (const float*)d_in[16];
    const float* bep2 = (const float*)d_in[17];
    const float* Wc2  = (const float*)d_in[18];
    const float* gc2  = (const float*)d_in[20];
    const float* bec2 = (const float*)d_in[21];
    // biases (d_in[7,11,15,19]) unused: constant channel shift cancels in BN.

    char* ws = (char*)d_ws;
    unsigned short* Xall = (unsigned short*)(ws + 0);
    unsigned short* Wb1  = (unsigned short*)(ws + 50331648);
    unsigned short* Wb2  = (unsigned short*)(ws + 50724864);
    float* ssb  = (float*)(ws + 50987008);
    float* psum = (float*)(ws + 50995200);
    float* psq  = (float*)(ws + 51519488);
    float* p2t  = (float*)(ws + 52043776);
    float* c2t  = (float*)(ws + 60432384);
    int*   idxw = (int*)  (ws + 68820992);
    float* wgtw = (float*)(ws + 69214208);
    unsigned short* Y1 = (unsigned short*)(ws + 52043776); // overlays transients
    float* out = (float*)d_out;

    dim3 tb(32, 8);
    transpose_kernel<<<dim3(32, 8, 8), tb, 0, stream>>>(points2, p2t, 256, 1024);
    transpose_kernel<<<dim3(32, 8, 8), tb, 0, stream>>>(colors2, c2t, 256, 1024);
    convw_kernel<<<320, 256, 0, stream>>>(Wp1, Wc1, Wp2, Wc2, Wb1, Wb2);
    top3_kernel<<<dim3(128, 8), 256, 0, stream>>>(xyz1, xyz2, idxw, wgtw);
    buildx_kernel<<<dim3(64, 8, 2), 256, 0, stream>>>(points1, colors1, p2t, c2t,
                                                      idxw, wgtw, Xall);
    gemm1_kernel<<<dim3(256, 2, 2), 256, 0, stream>>>(Xall, Wb1, Y1, psum, psq);
    reduce_kernel<<<dim3(2, 4), 256, 0, stream>>>(psum, psq, gp1, bep1, gc1, bec1, ssb, 0);
    gemm2_kernel<<<dim3(256, 2, 2), 256, 0, stream>>>(Y1, Wb2, ssb, out, psum, psq);
    reduce_kernel<<<dim3(2, 4), 256, 0, stream>>>(psum, psq, gp2, bep2, gc2, bec2, ssb, 1024);
    bnfinal_kernel<<<4096, 256, 0, stream>>>(out, ssb);
}

// Round 4
// 153.083 us; speedup vs baseline: 3.3297x; 1.2675x over previous
//
#include <hip/hip_runtime.h>
#include <cstdint>
#include <cstddef>

// PointNet++ FP, bf16-MFMA pipeline v3: gather fused into gemm1 staging.
// B=8, N=4096, S=1024, D1=128, D2=256, IN_C=384, MLP=[256,256], BN training.
//
//  transpose2b: points2/colors2 -> p2b/c2b bf16 [B][S][256]
//  convw: W* -> bf16 [o][k]
//  top3:  8 lanes/query, branchless scan + shfl_xor lexicographic merge
//  buildxA: points1/colors1 -> Xp bf16 [2][32768][128] (transpose only)
//  gemm1f: 128m x 256c, 8 waves; B-tile k<128 from Xp (gload_lds),
//          k>=128 gathered+weighted from p2b/c2b (reg-stage, swizzled ds_write);
//          Y1[m][c] bf16 + fused channel sum/sumsq partials
//  reduce(0): mean/var -> folded scale/shift (bias skipped: cancels in BN)
//  gemm2f: B = relu(bn(Y1)) reg-staged; y2b[m][o] bf16 + fused partials
//  reduce(1024); bnT: LDS-transpose + relu(bn) -> d_out [t][b][o][n] fp32
//
// ws layout (bytes), total 68,820,992:
//   y2b @0 (33,554,432) overlays: Xp@0 (16.8M) | p2b@16777216 | c2b@20971520
//     | idxw@25165824 | wgtw@25559040 | pad
//   Y1 @33554432 (33.5M) | Wb1 @67108864 | Wb2 @67502080
//   psum @67764224 | psq @68288512 | ssb @68812800

#define B_   8
#define N_   4096
#define S_   1024
#define D1_  128
#define D2_  256
#define INC_ 384
#define OC_  256
#define M_   (B_ * N_)

typedef __attribute__((ext_vector_type(8))) short sh8;
typedef __attribute__((ext_vector_type(4))) float f32x4;
typedef __attribute__((ext_vector_type(4))) unsigned short ush4;
typedef __attribute__((ext_vector_type(8))) unsigned short ush8;

__device__ __forceinline__ unsigned short bf16rne(float f) {
    union { float f; unsigned u; } v; v.f = f;
    return (unsigned short)((v.u + 0x7FFFu + ((v.u >> 16) & 1u)) >> 16);
}
__device__ __forceinline__ float bf2f(unsigned short h) {
    union { unsigned u; float f; } v; v.u = ((unsigned)h) << 16;
    return v.f;
}
__device__ __forceinline__ void gload16(const void* gsrc, void* lds) {
    __builtin_amdgcn_global_load_lds(
        (const __attribute__((address_space(1))) void*)gsrc,
        (__attribute__((address_space(3))) void*)lds, 16, 0, 0);
}

// ---------------------------------------------------------------- transpose->bf16
__global__ __launch_bounds__(256) void transpose2b_kernel(
    const float* __restrict__ src, unsigned short* __restrict__ dst)
{
    __shared__ float tile[32][33];
    const float* s = src + (size_t)blockIdx.z * D2_ * S_;
    unsigned short* d = dst + (size_t)blockIdx.z * S_ * D2_;
    int c = blockIdx.x * 32 + threadIdx.x;
#pragma unroll
    for (int i = 0; i < 4; ++i) {
        int r = blockIdx.y * 32 + threadIdx.y + i * 8;
        tile[threadIdx.y + i * 8][threadIdx.x] = s[(size_t)r * S_ + c];
    }
    __syncthreads();
    int r2 = blockIdx.y * 32 + threadIdx.x;
#pragma unroll
    for (int i = 0; i < 4; ++i) {
        int c2 = blockIdx.x * 32 + threadIdx.y + i * 8;
        d[(size_t)c2 * D2_ + r2] = bf16rne(tile[threadIdx.x][threadIdx.y + i * 8]);
    }
}

// ---------------------------------------------------------------- W -> bf16
__global__ __launch_bounds__(256) void convw_kernel(
    const float* __restrict__ Wp1, const float* __restrict__ Wc1,
    const float* __restrict__ Wp2, const float* __restrict__ Wc2,
    unsigned short* __restrict__ Wb1, unsigned short* __restrict__ Wb2)
{
    int e = (blockIdx.x * 256 + threadIdx.x) * 4;
    const float* src; unsigned short* dst; int off;
    if (e < 98304)       { src = Wp1; dst = Wb1;          off = e; }
    else if (e < 196608) { src = Wc1; dst = Wb1 + 98304;  off = e - 98304; }
    else if (e < 262144) { src = Wp2; dst = Wb2;          off = e - 196608; }
    else                 { src = Wc2; dst = Wb2 + 65536;  off = e - 262144; }
    float4 v = *(const float4*)(src + off);
    ush4 o; o[0] = bf16rne(v.x); o[1] = bf16rne(v.y); o[2] = bf16rne(v.z); o[3] = bf16rne(v.w);
    *(ush4*)(dst + off) = o;
}

// ---------------------------------------------------------------- top-3 NN
#define INS(pd, pi) { \
    bool l0 = (pd < d0) || (pd == d0 && pi < i0); \
    bool l1 = (pd < d1) || (pd == d1 && pi < i1); \
    bool l2 = (pd < d2) || (pd == d2 && pi < i2); \
    d2 = l1 ? d1 : (l2 ? pd : d2);  i2 = l1 ? i1 : (l2 ? pi : i2); \
    d1 = l0 ? d0 : (l1 ? pd : d1);  i1 = l0 ? i0 : (l1 ? pi : i1); \
    d0 = l0 ? pd : d0;              i0 = l0 ? pi : i0; \
}

__global__ __launch_bounds__(256) void top3_kernel(
    const float* __restrict__ xyz1, const float* __restrict__ xyz2,
    int* __restrict__ idxo, float* __restrict__ wo)
{
    __shared__ float4 sc[S_];
    const int b = blockIdx.y;
    const int tid = threadIdx.x;
    const float* x2 = xyz2 + (size_t)b * 3 * S_;
    for (int s = tid; s < S_; s += 256) {
        float xs = x2[s], ys = x2[S_ + s], zs = x2[2 * S_ + s];
        sc[s] = make_float4(xs, ys, zs, xs * xs + ys * ys + zs * zs);
    }
    __syncthreads();
    const int q = blockIdx.x * 32 + (tid >> 3);
    const int sub = tid & 7;
    const float* x1 = xyz1 + (size_t)b * 3 * N_;
    const float xq = x1[q], yq = x1[N_ + q], zq = x1[2 * N_ + q];
    const float n1 = xq * xq + yq * yq + zq * zq;
    float d0 = 3.4e38f, d1 = 3.4e38f, d2 = 3.4e38f;
    int i0 = 0, i1 = 0, i2 = 0;
#pragma unroll 4
    for (int j = 0; j < 128; ++j) {
        int s = j * 8 + sub;
        float4 v = sc[s];
        float dot = xq * v.x + yq * v.y + zq * v.z;
        float d = (n1 - 2.0f * dot) + v.w;
        bool c0 = d < d0, c1 = d < d1, c2 = d < d2;
        d2 = c1 ? d1 : (c2 ? d : d2); i2 = c1 ? i1 : (c2 ? s : i2);
        d1 = c0 ? d0 : (c1 ? d : d1); i1 = c0 ? i0 : (c1 ? s : i1);
        d0 = c0 ? d : d0;             i0 = c0 ? s : i0;
    }
#pragma unroll
    for (int off = 1; off < 8; off <<= 1) {
        float pd0 = __shfl_xor(d0, off), pd1 = __shfl_xor(d1, off), pd2 = __shfl_xor(d2, off);
        int   pi0 = __shfl_xor(i0, off), pi1 = __shfl_xor(i1, off), pi2 = __shfl_xor(i2, off);
        INS(pd0, pi0) INS(pd1, pi1) INS(pd2, pi2)
    }
    if (sub == 0) {
        float r0 = 1.f / (d0 + 1e-8f);
        float r1 = 1.f / (d1 + 1e-8f);
        float r2 = 1.f / (d2 + 1e-8f);
        float rs = r0 + r1 + r2;
        int base = (b * N_ + q) * 3;
        idxo[base] = i0; idxo[base + 1] = i1; idxo[base + 2] = i2;
        wo[base] = r0 / rs; wo[base + 1] = r1 / rs; wo[base + 2] = r2 / rs;
    }
}

// ---------------------------------------------------------------- Xp (transpose points1/colors1)
__global__ __launch_bounds__(256) void buildxA_kernel(
    const float* __restrict__ points1, const float* __restrict__ colors1,
    unsigned short* __restrict__ Xp)
{
    const int t = blockIdx.z, b = blockIdx.y, n0 = blockIdx.x * 64;
    const float* x1 = t ? colors1 : points1;
    const int tid = threadIdx.x;
    __shared__ float tileA[64][132];

#pragma unroll
    for (int it = 0; it < 8; ++it) {
        int fl4 = it * 256 + tid;
        int d = fl4 >> 4, nl = (fl4 & 15) * 4;
        float4 v = *(const float4*)(x1 + ((size_t)b * D1_ + d) * N_ + n0 + nl);
        tileA[nl][d] = v.x; tileA[nl + 1][d] = v.y; tileA[nl + 2][d] = v.z; tileA[nl + 3][d] = v.w;
    }
    __syncthreads();
    size_t mbase = (size_t)t * M_ + (size_t)b * N_ + n0;
#pragma unroll
    for (int it = 0; it < 4; ++it) {
        int e8 = it * 256 + tid;
        int r = e8 >> 4, dc = (e8 & 15) * 8;
        ush8 o;
#pragma unroll
        for (int j = 0; j < 8; ++j) o[j] = bf16rne(tileA[r][dc + j]);
        *(ush8*)(Xp + (mbase + r) * D1_ + dc) = o;
    }
}

// ---------------------------------------------------------------- GEMM1 (fused gather)
// 128m x 256c per block, 8 waves. D[row=c][col=m]; Y1[m][c] bf16 + stats.
__global__ __launch_bounds__(512) void gemm1f_kernel(
    const unsigned short* __restrict__ Xp,
    const unsigned short* __restrict__ p2b,
    const unsigned short* __restrict__ c2b,
    const int* __restrict__ idxw, const float* __restrict__ wgtw,
    const unsigned short* __restrict__ Wb1,
    unsigned short* __restrict__ Y1,
    float* __restrict__ psum, float* __restrict__ psq)
{
    const int t  = blockIdx.y;
    const int m0 = blockIdx.x * 128;
    const int bb = m0 >> 12;
    const unsigned short* Aw  = Wb1 + (size_t)t * (OC_ * INC_);
    const unsigned short* Xb  = Xp + (size_t)t * M_ * D1_;
    const unsigned short* f2b = t ? c2b : p2b;

    __shared__ __align__(16) char smem[49152];
    unsigned short* Alds = (unsigned short*)smem;          // [256][64]
    unsigned short* Blds = (unsigned short*)(smem + 32768); // [128][64]

    const int tid  = threadIdx.x;
    const int lane = tid & 63;
    const int wid  = tid >> 6;
    const int wc   = wid & 3;
    const int wm   = wid >> 2;
    const int srow = tid >> 3;                      // 0..63
    const int k8   = (tid & 7) * 8;                 // k group within tile
    const int sk   = ((tid & 7) ^ (srow & 7)) * 8;  // xor-pre-swizzled source k

    // hoist gather idx/weights for this thread's two staging rows
    int gi[2][3]; float gw[2][3];
#pragma unroll
    for (int p = 0; p < 2; ++p) {
        int base = (m0 + p * 64 + srow) * 3;
#pragma unroll
        for (int j = 0; j < 3; ++j) { gi[p][j] = idxw[base + j]; gw[p][j] = wgtw[base + j]; }
    }

    f32x4 acc[4][4];
#pragma unroll
    for (int i = 0; i < 4; ++i)
#pragma unroll
        for (int j = 0; j < 4; ++j) acc[i][j] = f32x4{0.f, 0.f, 0.f, 0.f};

    const int arow = wc * 64 + (lane & 15);
    const int brow = wm * 64 + (lane & 15);
    const int kgrp = (lane >> 4) * 16;

    for (int kc = 0; kc < INC_; kc += 64) {
        // A: W1 tile [256 c][64 k] via global_load_lds
#pragma unroll
        for (int p = 0; p < 4; ++p) {
            int row = p * 64 + srow;
            gload16(Aw + (size_t)row * INC_ + kc + sk,
                    (char*)Alds + p * 8192 + wid * 1024);
        }
        if (kc < D1_) {
            // B from Xp
#pragma unroll
            for (int p = 0; p < 2; ++p) {
                int row = p * 64 + srow;
                gload16(Xb + (size_t)(m0 + row) * D1_ + kc + sk,
                        (char*)Blds + p * 8192 + wid * 1024);
            }
        } else {
            // B = 3-way weighted gather from p2b/c2b (bf16), swizzled ds_write
            const int d0k = kc - D1_ + k8;
#pragma unroll
            for (int p = 0; p < 2; ++p) {
                int row = p * 64 + srow;
                ush8 a0 = *(const ush8*)(f2b + ((size_t)bb * S_ + gi[p][0]) * D2_ + d0k);
                ush8 a1 = *(const ush8*)(f2b + ((size_t)bb * S_ + gi[p][1]) * D2_ + d0k);
                ush8 a2 = *(const ush8*)(f2b + ((size_t)bb * S_ + gi[p][2]) * D2_ + d0k);
                ush8 ov;
#pragma unroll
                for (int j = 0; j < 8; ++j)
                    ov[j] = bf16rne(gw[p][0] * bf2f(a0[j]) + gw[p][1] * bf2f(a1[j])
                                  + gw[p][2] * bf2f(a2[j]));
                *(ush8*)((char*)Blds + row * 128 + ((k8 * 2) ^ ((row & 7) << 4))) = ov;
            }
        }
        __syncthreads();
#pragma unroll
        for (int kk = 0; kk < 2; ++kk) {
            sh8 a[4], b[4];
#pragma unroll
            for (int f = 0; f < 4; ++f) {
                int ra = arow + f * 16;
                int rb = brow + f * 16;
                int oa = ra * 128 + ((kk * 64 + kgrp) ^ ((ra & 7) << 4));
                int ob = rb * 128 + ((kk * 64 + kgrp) ^ ((rb & 7) << 4));
                a[f] = *(const sh8*)((const char*)Alds + oa);
                b[f] = *(const sh8*)((const char*)Blds + ob);
            }
#pragma unroll
            for (int fc = 0; fc < 4; ++fc)
#pragma unroll
                for (int fm = 0; fm < 4; ++fm)
                    acc[fc][fm] = __builtin_amdgcn_mfma_f32_16x16x32_bf16(
                        a[fc], b[fm], acc[fc][fm], 0, 0, 0);
        }
        __syncthreads();
    }

    // Y1[m][c] bf16
    const int mloc = m0 + wm * 64 + (lane & 15);
    const int chq  = (lane >> 4) * 4;
#pragma unroll
    for (int fm = 0; fm < 4; ++fm)
#pragma unroll
        for (int fc = 0; fc < 4; ++fc) {
            ush4 v;
#pragma unroll
            for (int r = 0; r < 4; ++r) v[r] = bf16rne(acc[fc][fm][r]);
            *(ush4*)(Y1 + ((size_t)t * M_ + mloc + fm * 16) * OC_
                      + wc * 64 + fc * 16 + chq) = v;
        }

    // fused stats, two-phase smem reuse: [contrib 32][ch 256 pad->264]
    float* sArr = (float*)smem;
    const int contrib = wm * 16 + (lane & 15);
#pragma unroll
    for (int ph = 0; ph < 2; ++ph) {
#pragma unroll
        for (int fc = 0; fc < 4; ++fc) {
            f32x4 s4;
#pragma unroll
            for (int r = 0; r < 4; ++r) {
                float s = 0.f;
#pragma unroll
                for (int fm = 0; fm < 4; ++fm) {
                    float v = acc[fc][fm][r];
                    s += ph ? v * v : v;
                }
                s4[r] = s;
            }
            *(f32x4*)&sArr[contrib * 264 + wc * 64 + fc * 16 + chq] = s4;
        }
        __syncthreads();
        if (tid < 256) {
            float s = 0.f;
#pragma unroll
            for (int k = 0; k < 32; ++k) s += sArr[((k + tid) & 31) * 264 + tid];
            float* dst = ph ? psq : psum;
            dst[((size_t)t * 256 + blockIdx.x) * 256 + tid] = s;
        }
        __syncthreads();
    }
}

// ---------------------------------------------------------------- stats reduce
__global__ __launch_bounds__(256) void reduce_kernel(
    const float* __restrict__ psum, const float* __restrict__ psq,
    const float* __restrict__ gp, const float* __restrict__ bep,
    const float* __restrict__ gc, const float* __restrict__ bec,
    float* __restrict__ ss, int layerOff)
{
    const int t = blockIdx.x, cs = blockIdx.y;
    const int tid = threadIdx.x;
    const int cl = tid & 63, grp = tid >> 6;
    const int c = cs * 64 + cl;
    float s = 0.f, q = 0.f;
    for (int k = grp; k < 256; k += 4) {
        s += psum[((size_t)t * 256 + k) * 256 + c];
        q += psq [((size_t)t * 256 + k) * 256 + c];
    }
    __shared__ float ls[4][64], lq[4][64];
    ls[grp][cl] = s; lq[grp][cl] = q;
    __syncthreads();
    if (tid < 64) {
        s = ls[0][cl] + ls[1][cl] + ls[2][cl] + ls[3][cl];
        q = lq[0][cl] + lq[1][cl] + lq[2][cl] + lq[3][cl];
        float mean = s * (1.f / (float)M_);
        float var  = q * (1.f / (float)M_) - mean * mean;
        float inv  = rsqrtf(var + 1e-5f);
        float g = (t ? gc : gp)[c], be = (t ? bec : bep)[c];
        float sc = g * inv;
        ss[layerOff + t * 256 + c]       = sc;
        ss[layerOff + 512 + t * 256 + c] = be - mean * sc;
    }
}

// ---------------------------------------------------------------- GEMM2
__global__ __launch_bounds__(512) void gemm2f_kernel(
    const unsigned short* __restrict__ Y1,
    const unsigned short* __restrict__ Wb2,
    const float* __restrict__ ss,
    unsigned short* __restrict__ y2b,
    float* __restrict__ psum, float* __restrict__ psq)
{
    const int t  = blockIdx.y;
    const int m0 = blockIdx.x * 128;
    const unsigned short* Aw = Wb2 + (size_t)t * (OC_ * OC_);
    const unsigned short* By = Y1 + (size_t)t * M_ * OC_;

    __shared__ __align__(16) char smem[49152];
    unsigned short* Alds = (unsigned short*)smem;
    unsigned short* Blds = (unsigned short*)(smem + 32768);
    __shared__ float Slds[256], Hlds[256];

    const int tid  = threadIdx.x;
    const int lane = tid & 63;
    const int wid  = tid >> 6;
    const int wc   = wid & 3;
    const int wm   = wid >> 2;
    const int srow = tid >> 3;
    const int k8   = (tid & 7) * 8;
    const int sk   = ((tid & 7) ^ (srow & 7)) * 8;

    if (tid < 256) { Slds[tid] = ss[t * 256 + tid]; Hlds[tid] = ss[512 + t * 256 + tid]; }
    __syncthreads();

    f32x4 acc[4][4];
#pragma unroll
    for (int i = 0; i < 4; ++i)
#pragma unroll
        for (int j = 0; j < 4; ++j) acc[i][j] = f32x4{0.f, 0.f, 0.f, 0.f};

    const int arow = wc * 64 + (lane & 15);
    const int brow = wm * 64 + (lane & 15);
    const int kgrp = (lane >> 4) * 16;

    for (int kc = 0; kc < OC_; kc += 64) {
#pragma unroll
        for (int p = 0; p < 4; ++p) {
            int row = p * 64 + srow;
            gload16(Aw + (size_t)row * OC_ + kc + sk,
                    (char*)Alds + p * 8192 + wid * 1024);
        }
#pragma unroll
        for (int p = 0; p < 2; ++p) {
            int row = p * 64 + srow;
            ush8 yv = *(const ush8*)(By + (size_t)(m0 + row) * OC_ + kc + k8);
            ush8 ov;
#pragma unroll
            for (int j = 0; j < 8; ++j) {
                float y = bf2f(yv[j]);
                ov[j] = bf16rne(fmaxf(0.f, fmaf(y, Slds[kc + k8 + j], Hlds[kc + k8 + j])));
            }
            *(ush8*)((char*)Blds + row * 128 + ((k8 * 2) ^ ((row & 7) << 4))) = ov;
        }
        __syncthreads();
#pragma unroll
        for (int kk = 0; kk < 2; ++kk) {
            sh8 a[4], b[4];
#pragma unroll
            for (int f = 0; f < 4; ++f) {
                int ra = arow + f * 16;
                int rb = brow + f * 16;
                int oa = ra * 128 + ((kk * 64 + kgrp) ^ ((ra & 7) << 4));
                int ob = rb * 128 + ((kk * 64 + kgrp) ^ ((rb & 7) << 4));
                a[f] = *(const sh8*)((const char*)Alds + oa);
                b[f] = *(const sh8*)((const char*)Blds + ob);
            }
#pragma unroll
            for (int fc = 0; fc < 4; ++fc)
#pragma unroll
                for (int fm = 0; fm < 4; ++fm)
                    acc[fc][fm] = __builtin_amdgcn_mfma_f32_16x16x32_bf16(
                        a[fc], b[fm], acc[fc][fm], 0, 0, 0);
        }
        __syncthreads();
    }

    const int mloc = m0 + wm * 64 + (lane & 15);
    const int chq  = (lane >> 4) * 4;
#pragma unroll
    for (int fm = 0; fm < 4; ++fm)
#pragma unroll
        for (int fc = 0; fc < 4; ++fc) {
            ush4 v;
#pragma unroll
            for (int r = 0; r < 4; ++r) v[r] = bf16rne(acc[fc][fm][r]);
            *(ush4*)(y2b + ((size_t)t * M_ + mloc + fm * 16) * OC_
                      + wc * 64 + fc * 16 + chq) = v;
        }

    float* sArr = (float*)smem;
    const int contrib = wm * 16 + (lane & 15);
#pragma unroll
    for (int ph = 0; ph < 2; ++ph) {
#pragma unroll
        for (int fc = 0; fc < 4; ++fc) {
            f32x4 s4;
#pragma unroll
            for (int r = 0; r < 4; ++r) {
                float s = 0.f;
#pragma unroll
                for (int fm = 0; fm < 4; ++fm) {
                    float v = acc[fc][fm][r];
                    s += ph ? v * v : v;
                }
                s4[r] = s;
            }
            *(f32x4*)&sArr[contrib * 264 + wc * 64 + fc * 16 + chq] = s4;
        }
        __syncthreads();
        if (tid < 256) {
            float s = 0.f;
#pragma unroll
            for (int k = 0; k < 32; ++k) s += sArr[((k + tid) & 31) * 264 + tid];
            float* dst = ph ? psq : psum;
            dst[((size_t)t * 256 + blockIdx.x) * 256 + tid] = s;
        }
        __syncthreads();
    }
}

// ---------------------------------------------------------------- BN+ReLU + transpose to out
__global__ __launch_bounds__(256) void bnT_kernel(
    const unsigned short* __restrict__ y2b, const float* __restrict__ ss,
    float* __restrict__ out)
{
    const int z = blockIdx.z;                 // t*8 + b
    const int t = z >> 3, b = z & 7;
    const int o0 = blockIdx.y * 64;
    const int n0 = blockIdx.x * 64;
    const int tid = threadIdx.x;
    __shared__ unsigned short tile[64][72];

    const unsigned short* src = y2b + ((size_t)t * M_ + (size_t)b * N_ + n0) * OC_ + o0;
#pragma unroll
    for (int it = 0; it < 2; ++it) {
        int u = it * 256 + tid;
        int m_l = u >> 3, o8 = (u & 7) * 8;
        *(ush8*)&tile[m_l][o8] = *(const ush8*)(src + (size_t)m_l * OC_ + o8);
    }
    __syncthreads();
#pragma unroll
    for (int it = 0; it < 4; ++it) {
        int v = it * 256 + tid;
        int o_l = v >> 4, n4 = (v & 15) * 4;
        int o = o0 + o_l;
        float sc = ss[1024 + t * 256 + o];
        float sh = ss[1536 + t * 256 + o];
        float4 w;
        w.x = fmaxf(0.f, fmaf(bf2f(tile[n4][o_l]),     sc, sh));
        w.y = fmaxf(0.f, fmaf(bf2f(tile[n4 + 1][o_l]), sc, sh));
        w.z = fmaxf(0.f, fmaf(bf2f(tile[n4 + 2][o_l]), sc, sh));
        w.w = fmaxf(0.f, fmaf(bf2f(tile[n4 + 3][o_l]), sc, sh));
        *(float4*)(out + (((size_t)t * B_ + b) * OC_ + o) * N_ + n0 + n4) = w;
    }
}

// ---------------------------------------------------------------- launch
extern "C" void kernel_launch(void* const* d_in, const int* in_sizes, int n_in,
                              void* d_out, int out_size, void* d_ws, size_t ws_size,
                              hipStream_t stream)
{
    const float* xyz1    = (const float*)d_in[0];
    const float* xyz2    = (const float*)d_in[1];
    const float* points1 = (const float*)d_in[2];
    const float* points2 = (const float*)d_in[3];
    const float* colors1 = (const float*)d_in[4];
    const float* colors2 = (const float*)d_in[5];
    const float* Wp1  = (const float*)d_in[6];
    const float* gp1  = (const float*)d_in[8];
    const float* bep1 = (const float*)d_in[9];
    const float* Wc1  = (const float*)d_in[10];
    const float* gc1  = (const float*)d_in[12];
    const float* bec1 = (const float*)d_in[13];
    const float* Wp2  = (const float*)d_in[14];
    const float* gp2  = (const float*)d_in[16];
    const float* bep2 = (const float*)d_in[17];
    const float* Wc2  = (const float*)d_in[18];
    const float* gc2  = (const float*)d_in[20];
    const float* bec2 = (const float*)d_in[21];
    // biases (d_in[7,11,15,19]) unused: constant channel shift cancels in BN.

    char* ws = (char*)d_ws;
    unsigned short* y2b  = (unsigned short*)(ws + 0);
    unsigned short* Xp   = (unsigned short*)(ws + 0);         // overlays y2b
    unsigned short* p2b  = (unsigned short*)(ws + 16777216);
    unsigned short* c2b  = (unsigned short*)(ws + 20971520);
    int*   idxw = (int*)  (ws + 25165824);
    float* wgtw = (float*)(ws + 25559040);
    unsigned short* Y1   = (unsigned short*)(ws + 33554432);
    unsigned short* Wb1  = (unsigned short*)(ws + 67108864);
    unsigned short* Wb2  = (unsigned short*)(ws + 67502080);
    float* psum = (float*)(ws + 67764224);
    float* psq  = (float*)(ws + 68288512);
    float* ssb  = (float*)(ws + 68812800);
    float* out  = (float*)d_out;

    dim3 tb(32, 8);
    transpose2b_kernel<<<dim3(32, 8, 8), tb, 0, stream>>>(points2, p2b);
    transpose2b_kernel<<<dim3(32, 8, 8), tb, 0, stream>>>(colors2, c2b);
    convw_kernel<<<320, 256, 0, stream>>>(Wp1, Wc1, Wp2, Wc2, Wb1, Wb2);
    top3_kernel<<<dim3(128, 8), 256, 0, stream>>>(xyz1, xyz2, idxw, wgtw);
    buildxA_kernel<<<dim3(64, 8, 2), 256, 0, stream>>>(points1, colors1, Xp);
    gemm1f_kernel<<<dim3(256, 2), 512, 0, stream>>>(Xp, p2b, c2b, idxw, wgtw,
                                                    Wb1, Y1, psum, psq);
    reduce_kernel<<<dim3(2, 4), 256, 0, stream>>>(psum, psq, gp1, bep1, gc1, bec1, ssb, 0);
    gemm2f_kernel<<<dim3(256, 2), 512, 0, stream>>>(Y1, Wb2, ssb, y2b, psum, psq);
    reduce_kernel<<<dim3(2, 4), 256, 0, stream>>>(psum, psq, gp2, bep2, gc2, bec2, ssb, 1024);
    bnT_kernel<<<dim3(64, 4, 16), 256, 0, stream>>>(y2b, ssb, out);
}

// Round 5
// 133.240 us; speedup vs baseline: 3.8256x; 1.1489x over previous
//
#include <hip/hip_runtime.h>
#include <cstdint>
#include <cstddef>

// PointNet++ FP, bf16-MFMA pipeline v4: 256x256 prefetch-dbuf GEMMs.
// B=8, N=4096, S=1024, D1=128, D2=256, IN_C=384, MLP=[256,256], BN training.
//
//  transpose2b: points2/colors2 -> p2b/c2b bf16 [B][S][256]
//  convw: W* -> bf16 [o][k]
//  top3:  8 lanes/query, branchless scan + shfl_xor lexicographic merge
//  buildxA: points1/colors1 -> Xp bf16 [2][32768][128]
//  gemm1f: 256m x 256c, 8 waves, LDS double-buffer prefetch (1 barrier/K-step);
//          B-tile k<128 from Xp (gload_lds), k>=128 gathered from p2b/c2b;
//          Y1[m][c] bf16 + fused channel sum/sumsq partials
//  reduce(0); gemm2f: same structure, B = relu(bn(Y1)); y2b bf16 + partials
//  reduce(1024); bnT: LDS-transpose + relu(bn) -> d_out [t][b][o][n] fp32
//
// ws layout (bytes), total 68,952,064:
//   y2b @0 (33.5M) overlays: Xp@0 | p2b@16777216 | c2b@20971520
//     | idxw@25165824 | wgtw@25559040
//   Y1 @33554432 | Wb1 @67108864 | Wb2 @67895296
//   psum @68419584 | psq @68681728 | ssb @68943872

#define B_   8
#define N_   4096
#define S_   1024
#define D1_  128
#define D2_  256
#define INC_ 384
#define OC_  256
#define M_   (B_ * N_)

typedef __attribute__((ext_vector_type(8))) short sh8;
typedef __attribute__((ext_vector_type(4))) float f32x4;
typedef __attribute__((ext_vector_type(4))) unsigned short ush4;
typedef __attribute__((ext_vector_type(8))) unsigned short ush8;

__device__ __forceinline__ unsigned short bf16rne(float f) {
    union { float f; unsigned u; } v; v.f = f;
    return (unsigned short)((v.u + 0x7FFFu + ((v.u >> 16) & 1u)) >> 16);
}
__device__ __forceinline__ float bf2f(unsigned short h) {
    union { unsigned u; float f; } v; v.u = ((unsigned)h) << 16;
    return v.f;
}
__device__ __forceinline__ void gload16(const void* gsrc, void* lds) {
    __builtin_amdgcn_global_load_lds(
        (const __attribute__((address_space(1))) void*)gsrc,
        (__attribute__((address_space(3))) void*)lds, 16, 0, 0);
}

// ---------------------------------------------------------------- transpose->bf16
__global__ __launch_bounds__(256) void transpose2b_kernel(
    const float* __restrict__ src, unsigned short* __restrict__ dst)
{
    __shared__ float tile[32][33];
    const float* s = src + (size_t)blockIdx.z * D2_ * S_;
    unsigned short* d = dst + (size_t)blockIdx.z * S_ * D2_;
    int c = blockIdx.x * 32 + threadIdx.x;
#pragma unroll
    for (int i = 0; i < 4; ++i) {
        int r = blockIdx.y * 32 + threadIdx.y + i * 8;
        tile[threadIdx.y + i * 8][threadIdx.x] = s[(size_t)r * S_ + c];
    }
    __syncthreads();
    int r2 = blockIdx.y * 32 + threadIdx.x;
#pragma unroll
    for (int i = 0; i < 4; ++i) {
        int c2 = blockIdx.x * 32 + threadIdx.y + i * 8;
        d[(size_t)c2 * D2_ + r2] = bf16rne(tile[threadIdx.x][threadIdx.y + i * 8]);
    }
}

// ---------------------------------------------------------------- W -> bf16
__global__ __launch_bounds__(256) void convw_kernel(
    const float* __restrict__ Wp1, const float* __restrict__ Wc1,
    const float* __restrict__ Wp2, const float* __restrict__ Wc2,
    unsigned short* __restrict__ Wb1, unsigned short* __restrict__ Wb2)
{
    int e = (blockIdx.x * 256 + threadIdx.x) * 4;
    const float* src; unsigned short* dst; int off;
    if (e < 98304)       { src = Wp1; dst = Wb1;          off = e; }
    else if (e < 196608) { src = Wc1; dst = Wb1 + 98304;  off = e - 98304; }
    else if (e < 262144) { src = Wp2; dst = Wb2;          off = e - 196608; }
    else                 { src = Wc2; dst = Wb2 + 65536;  off = e - 262144; }
    float4 v = *(const float4*)(src + off);
    ush4 o; o[0] = bf16rne(v.x); o[1] = bf16rne(v.y); o[2] = bf16rne(v.z); o[3] = bf16rne(v.w);
    *(ush4*)(dst + off) = o;
}

// ---------------------------------------------------------------- top-3 NN
#define INS(pd, pi) { \
    bool l0 = (pd < d0) || (pd == d0 && pi < i0); \
    bool l1 = (pd < d1) || (pd == d1 && pi < i1); \
    bool l2 = (pd < d2) || (pd == d2 && pi < i2); \
    d2 = l1 ? d1 : (l2 ? pd : d2);  i2 = l1 ? i1 : (l2 ? pi : i2); \
    d1 = l0 ? d0 : (l1 ? pd : d1);  i1 = l0 ? i0 : (l1 ? pi : i1); \
    d0 = l0 ? pd : d0;              i0 = l0 ? pi : i0; \
}

__global__ __launch_bounds__(256) void top3_kernel(
    const float* __restrict__ xyz1, const float* __restrict__ xyz2,
    int* __restrict__ idxo, float* __restrict__ wo)
{
    __shared__ float4 sc[S_];
    const int b = blockIdx.y;
    const int tid = threadIdx.x;
    const float* x2 = xyz2 + (size_t)b * 3 * S_;
    for (int s = tid; s < S_; s += 256) {
        float xs = x2[s], ys = x2[S_ + s], zs = x2[2 * S_ + s];
        sc[s] = make_float4(xs, ys, zs, xs * xs + ys * ys + zs * zs);
    }
    __syncthreads();
    const int q = blockIdx.x * 32 + (tid >> 3);
    const int sub = tid & 7;
    const float* x1 = xyz1 + (size_t)b * 3 * N_;
    const float xq = x1[q], yq = x1[N_ + q], zq = x1[2 * N_ + q];
    const float n1 = xq * xq + yq * yq + zq * zq;
    float d0 = 3.4e38f, d1 = 3.4e38f, d2 = 3.4e38f;
    int i0 = 0, i1 = 0, i2 = 0;
#pragma unroll 4
    for (int j = 0; j < 128; ++j) {
        int s = j * 8 + sub;
        float4 v = sc[s];
        float dot = xq * v.x + yq * v.y + zq * v.z;
        float d = (n1 - 2.0f * dot) + v.w;
        bool c0 = d < d0, c1 = d < d1, c2 = d < d2;
        d2 = c1 ? d1 : (c2 ? d : d2); i2 = c1 ? i1 : (c2 ? s : i2);
        d1 = c0 ? d0 : (c1 ? d : d1); i1 = c0 ? i0 : (c1 ? s : i1);
        d0 = c0 ? d : d0;             i0 = c0 ? s : i0;
    }
#pragma unroll
    for (int off = 1; off < 8; off <<= 1) {
        float pd0 = __shfl_xor(d0, off), pd1 = __shfl_xor(d1, off), pd2 = __shfl_xor(d2, off);
        int   pi0 = __shfl_xor(i0, off), pi1 = __shfl_xor(i1, off), pi2 = __shfl_xor(i2, off);
        INS(pd0, pi0) INS(pd1, pi1) INS(pd2, pi2)
    }
    if (sub == 0) {
        float r0 = 1.f / (d0 + 1e-8f);
        float r1 = 1.f / (d1 + 1e-8f);
        float r2 = 1.f / (d2 + 1e-8f);
        float rs = r0 + r1 + r2;
        int base = (b * N_ + q) * 3;
        idxo[base] = i0; idxo[base + 1] = i1; idxo[base + 2] = i2;
        wo[base] = r0 / rs; wo[base + 1] = r1 / rs; wo[base + 2] = r2 / rs;
    }
}

// ---------------------------------------------------------------- Xp transpose
__global__ __launch_bounds__(256) void buildxA_kernel(
    const float* __restrict__ points1, const float* __restrict__ colors1,
    unsigned short* __restrict__ Xp)
{
    const int t = blockIdx.z, b = blockIdx.y, n0 = blockIdx.x * 64;
    const float* x1 = t ? colors1 : points1;
    const int tid = threadIdx.x;
    __shared__ float tileA[64][132];

#pragma unroll
    for (int it = 0; it < 8; ++it) {
        int fl4 = it * 256 + tid;
        int d = fl4 >> 4, nl = (fl4 & 15) * 4;
        float4 v = *(const float4*)(x1 + ((size_t)b * D1_ + d) * N_ + n0 + nl);
        tileA[nl][d] = v.x; tileA[nl + 1][d] = v.y; tileA[nl + 2][d] = v.z; tileA[nl + 3][d] = v.w;
    }
    __syncthreads();
    size_t mbase = (size_t)t * M_ + (size_t)b * N_ + n0;
#pragma unroll
    for (int it = 0; it < 4; ++it) {
        int e8 = it * 256 + tid;
        int r = e8 >> 4, dc = (e8 & 15) * 8;
        ush8 o;
#pragma unroll
        for (int j = 0; j < 8; ++j) o[j] = bf16rne(tileA[r][dc + j]);
        *(ush8*)(Xp + (mbase + r) * D1_ + dc) = o;
    }
}

// ---------------------------------------------------------------- GEMM1 (prefetch dbuf)
// 256m x 256c per block, 8 waves. D[row=c][col=m]; Y1[m][c] bf16 + stats.
__global__ __launch_bounds__(512, 2) void gemm1f_kernel(
    const unsigned short* __restrict__ Xp,
    const unsigned short* __restrict__ p2b,
    const unsigned short* __restrict__ c2b,
    const int* __restrict__ idxw, const float* __restrict__ wgtw,
    const unsigned short* __restrict__ Wb1,
    unsigned short* __restrict__ Y1,
    float* __restrict__ psum, float* __restrict__ psq)
{
    const int t  = blockIdx.y;
    const int m0 = blockIdx.x * 256;
    const int bb = m0 >> 12;
    const unsigned short* Aw  = Wb1 + (size_t)t * (OC_ * INC_);
    const unsigned short* Xb  = Xp + (size_t)t * M_ * D1_;
    const unsigned short* f2b = t ? c2b : p2b;

    // A bufs @0,@32768 ; B bufs @65536,@98304  (128 KiB total)
    __shared__ __align__(16) char smem[131072];

    const int tid  = threadIdx.x;
    const int lane = tid & 63;
    const int wid  = tid >> 6;
    const int wc   = wid & 3;     // c quadrant (64)
    const int wm   = wid >> 2;    // m half (128)
    const int srow = tid >> 3;    // 0..63
    const int k8   = (tid & 7) * 8;
    const int sk   = ((tid & 7) ^ (srow & 7)) * 8;
    const int kgrp = (lane >> 4) * 16;

    int gi[4][3]; float gw[4][3];
#pragma unroll
    for (int p = 0; p < 4; ++p) {
        int base = (m0 + p * 64 + srow) * 3;
#pragma unroll
        for (int j = 0; j < 3; ++j) { gi[p][j] = idxw[base + j]; gw[p][j] = wgtw[base + j]; }
    }

    f32x4 acc[4][8];
#pragma unroll
    for (int i = 0; i < 4; ++i)
#pragma unroll
        for (int j = 0; j < 8; ++j) acc[i][j] = f32x4{0.f, 0.f, 0.f, 0.f};

    auto stageA = [&](int buf, int kc) {
#pragma unroll
        for (int p = 0; p < 4; ++p)
            gload16(Aw + (size_t)(p * 64 + srow) * INC_ + kc + sk,
                    smem + buf * 32768 + p * 8192 + wid * 1024);
    };
    auto stageBX = [&](int buf, int kc) {
#pragma unroll
        for (int p = 0; p < 4; ++p)
            gload16(Xb + (size_t)(m0 + p * 64 + srow) * D1_ + kc + sk,
                    smem + 65536 + buf * 32768 + p * 8192 + wid * 1024);
    };
    auto stageBG = [&](int buf, int kc) {
        const int d0k = kc - D1_ + k8;
#pragma unroll
        for (int p = 0; p < 4; ++p) {
            int row = p * 64 + srow;
            ush8 a0 = *(const ush8*)(f2b + ((size_t)bb * S_ + gi[p][0]) * D2_ + d0k);
            ush8 a1 = *(const ush8*)(f2b + ((size_t)bb * S_ + gi[p][1]) * D2_ + d0k);
            ush8 a2 = *(const ush8*)(f2b + ((size_t)bb * S_ + gi[p][2]) * D2_ + d0k);
            ush8 ov;
#pragma unroll
            for (int j = 0; j < 8; ++j)
                ov[j] = bf16rne(gw[p][0] * bf2f(a0[j]) + gw[p][1] * bf2f(a1[j])
                              + gw[p][2] * bf2f(a2[j]));
            *(ush8*)(smem + 65536 + buf * 32768 + row * 128
                     + ((k8 * 2) ^ ((row & 7) << 4))) = ov;
        }
    };
    auto compute = [&](int buf) {
#pragma unroll
        for (int kk = 0; kk < 2; ++kk) {
            sh8 a[4], b[8];
#pragma unroll
            for (int f = 0; f < 4; ++f) {
                int ra = wc * 64 + (lane & 15) + f * 16;
                a[f] = *(const sh8*)(smem + buf * 32768 + ra * 128
                        + ((kk * 64 + kgrp) ^ ((ra & 7) << 4)));
            }
#pragma unroll
            for (int f = 0; f < 8; ++f) {
                int rb = wm * 128 + (lane & 15) + f * 16;
                b[f] = *(const sh8*)(smem + 65536 + buf * 32768 + rb * 128
                        + ((kk * 64 + kgrp) ^ ((rb & 7) << 4)));
            }
#pragma unroll
            for (int fc = 0; fc < 4; ++fc)
#pragma unroll
                for (int fm = 0; fm < 8; ++fm)
                    acc[fc][fm] = __builtin_amdgcn_mfma_f32_16x16x32_bf16(
                        a[fc], b[fm], acc[fc][fm], 0, 0, 0);
        }
    };

    stageA(0, 0); stageBX(0, 0);
    __syncthreads();
    int cur = 0;
    for (int step = 0; step < 6; ++step) {
        int kcn = (step + 1) * 64;
        if (step < 5) {
            stageA(cur ^ 1, kcn);
            if (kcn < D1_) stageBX(cur ^ 1, kcn);
            else           stageBG(cur ^ 1, kcn);
        }
        compute(cur);
        __syncthreads();      // drains next-buf loads (overlapped with MFMA above)
        cur ^= 1;
    }

    // Y1[m][c] bf16
    const int mrow = m0 + wm * 128 + (lane & 15);
    const int chq  = (lane >> 4) * 4;
#pragma unroll
    for (int fm = 0; fm < 8; ++fm)
#pragma unroll
        for (int fc = 0; fc < 4; ++fc) {
            ush4 v;
#pragma unroll
            for (int r = 0; r < 4; ++r) v[r] = bf16rne(acc[fc][fm][r]);
            *(ush4*)(Y1 + ((size_t)t * M_ + mrow + fm * 16) * OC_
                      + wc * 64 + fc * 16 + chq) = v;
        }

    // fused stats: sArr[contrib 32][ch 256 pad 264]
    float* sArr = (float*)smem;
    const int contrib = wm * 16 + (lane & 15);
#pragma unroll
    for (int ph = 0; ph < 2; ++ph) {
#pragma unroll
        for (int fc = 0; fc < 4; ++fc) {
            f32x4 s4;
#pragma unroll
            for (int r = 0; r < 4; ++r) {
                float s = 0.f;
#pragma unroll
                for (int fm = 0; fm < 8; ++fm) { float v = acc[fc][fm][r]; s += ph ? v * v : v; }
                s4[r] = s;
            }
            *(f32x4*)&sArr[contrib * 264 + wc * 64 + fc * 16 + chq] = s4;
        }
        __syncthreads();
        if (tid < 256) {
            float s = 0.f;
#pragma unroll
            for (int k = 0; k < 32; ++k) s += sArr[((k + tid) & 31) * 264 + tid];
            (ph ? psq : psum)[((size_t)t * 128 + blockIdx.x) * 256 + tid] = s;
        }
        __syncthreads();
    }
}

// ---------------------------------------------------------------- stats reduce
__global__ __launch_bounds__(256) void reduce_kernel(
    const float* __restrict__ psum, const float* __restrict__ psq,
    const float* __restrict__ gp, const float* __restrict__ bep,
    const float* __restrict__ gc, const float* __restrict__ bec,
    float* __restrict__ ss, int layerOff)
{
    const int t = blockIdx.x, cs = blockIdx.y;
    const int tid = threadIdx.x;
    const int cl = tid & 63, grp = tid >> 6;
    const int c = cs * 64 + cl;
    float s = 0.f, q = 0.f;
    for (int k = grp; k < 128; k += 4) {
        s += psum[((size_t)t * 128 + k) * 256 + c];
        q += psq [((size_t)t * 128 + k) * 256 + c];
    }
    __shared__ float ls[4][64], lq[4][64];
    ls[grp][cl] = s; lq[grp][cl] = q;
    __syncthreads();
    if (tid < 64) {
        s = ls[0][cl] + ls[1][cl] + ls[2][cl] + ls[3][cl];
        q = lq[0][cl] + lq[1][cl] + lq[2][cl] + lq[3][cl];
        float mean = s * (1.f / (float)M_);
        float var  = q * (1.f / (float)M_) - mean * mean;
        float inv  = rsqrtf(var + 1e-5f);
        float g = (t ? gc : gp)[c], be = (t ? bec : bep)[c];
        float sc = g * inv;
        ss[layerOff + t * 256 + c]       = sc;
        ss[layerOff + 512 + t * 256 + c] = be - mean * sc;
    }
}

// ---------------------------------------------------------------- GEMM2 (prefetch dbuf)
__global__ __launch_bounds__(512, 2) void gemm2f_kernel(
    const unsigned short* __restrict__ Y1,
    const unsigned short* __restrict__ Wb2,
    const float* __restrict__ ss,
    unsigned short* __restrict__ y2b,
    float* __restrict__ psum, float* __restrict__ psq)
{
    const int t  = blockIdx.y;
    const int m0 = blockIdx.x * 256;
    const unsigned short* Aw = Wb2 + (size_t)t * (OC_ * OC_);
    const unsigned short* By = Y1 + (size_t)t * M_ * OC_;

    __shared__ __align__(16) char smem[131072];
    __shared__ float Slds[256], Hlds[256];

    const int tid  = threadIdx.x;
    const int lane = tid & 63;
    const int wid  = tid >> 6;
    const int wc   = wid & 3;
    const int wm   = wid >> 2;
    const int srow = tid >> 3;
    const int k8   = (tid & 7) * 8;
    const int sk   = ((tid & 7) ^ (srow & 7)) * 8;
    const int kgrp = (lane >> 4) * 16;

    if (tid < 256) { Slds[tid] = ss[t * 256 + tid]; Hlds[tid] = ss[512 + t * 256 + tid]; }
    __syncthreads();

    f32x4 acc[4][8];
#pragma unroll
    for (int i = 0; i < 4; ++i)
#pragma unroll
        for (int j = 0; j < 8; ++j) acc[i][j] = f32x4{0.f, 0.f, 0.f, 0.f};

    auto stageA = [&](int buf, int kc) {
#pragma unroll
        for (int p = 0; p < 4; ++p)
            gload16(Aw + (size_t)(p * 64 + srow) * OC_ + kc + sk,
                    smem + buf * 32768 + p * 8192 + wid * 1024);
    };
    auto stageBY = [&](int buf, int kc) {
#pragma unroll
        for (int p = 0; p < 4; ++p) {
            int row = p * 64 + srow;
            ush8 yv = *(const ush8*)(By + (size_t)(m0 + row) * OC_ + kc + k8);
            ush8 ov;
#pragma unroll
            for (int j = 0; j < 8; ++j) {
                float y = bf2f(yv[j]);
                ov[j] = bf16rne(fmaxf(0.f, fmaf(y, Slds[kc + k8 + j], Hlds[kc + k8 + j])));
            }
            *(ush8*)(smem + 65536 + buf * 32768 + row * 128
                     + ((k8 * 2) ^ ((row & 7) << 4))) = ov;
        }
    };
    auto compute = [&](int buf) {
#pragma unroll
        for (int kk = 0; kk < 2; ++kk) {
            sh8 a[4], b[8];
#pragma unroll
            for (int f = 0; f < 4; ++f) {
                int ra = wc * 64 + (lane & 15) + f * 16;
                a[f] = *(const sh8*)(smem + buf * 32768 + ra * 128
                        + ((kk * 64 + kgrp) ^ ((ra & 7) << 4)));
            }
#pragma unroll
            for (int f = 0; f < 8; ++f) {
                int rb = wm * 128 + (lane & 15) + f * 16;
                b[f] = *(const sh8*)(smem + 65536 + buf * 32768 + rb * 128
                        + ((kk * 64 + kgrp) ^ ((rb & 7) << 4)));
            }
#pragma unroll
            for (int fc = 0; fc < 4; ++fc)
#pragma unroll
                for (int fm = 0; fm < 8; ++fm)
                    acc[fc][fm] = __builtin_amdgcn_mfma_f32_16x16x32_bf16(
                        a[fc], b[fm], acc[fc][fm], 0, 0, 0);
        }
    };

    stageA(0, 0); stageBY(0, 0);
    __syncthreads();
    int cur = 0;
    for (int step = 0; step < 4; ++step) {
        int kcn = (step + 1) * 64;
        if (step < 3) { stageA(cur ^ 1, kcn); stageBY(cur ^ 1, kcn); }
        compute(cur);
        __syncthreads();
        cur ^= 1;
    }

    const int mrow = m0 + wm * 128 + (lane & 15);
    const int chq  = (lane >> 4) * 4;
#pragma unroll
    for (int fm = 0; fm < 8; ++fm)
#pragma unroll
        for (int fc = 0; fc < 4; ++fc) {
            ush4 v;
#pragma unroll
            for (int r = 0; r < 4; ++r) v[r] = bf16rne(acc[fc][fm][r]);
            *(ush4*)(y2b + ((size_t)t * M_ + mrow + fm * 16) * OC_
                      + wc * 64 + fc * 16 + chq) = v;
        }

    float* sArr = (float*)smem;
    const int contrib = wm * 16 + (lane & 15);
#pragma unroll
    for (int ph = 0; ph < 2; ++ph) {
#pragma unroll
        for (int fc = 0; fc < 4; ++fc) {
            f32x4 s4;
#pragma unroll
            for (int r = 0; r < 4; ++r) {
                float s = 0.f;
#pragma unroll
                for (int fm = 0; fm < 8; ++fm) { float v = acc[fc][fm][r]; s += ph ? v * v : v; }
                s4[r] = s;
            }
            *(f32x4*)&sArr[contrib * 264 + wc * 64 + fc * 16 + chq] = s4;
        }
        __syncthreads();
        if (tid < 256) {
            float s = 0.f;
#pragma unroll
            for (int k = 0; k < 32; ++k) s += sArr[((k + tid) & 31) * 264 + tid];
            (ph ? psq : psum)[((size_t)t * 128 + blockIdx.x) * 256 + tid] = s;
        }
        __syncthreads();
    }
}

// ---------------------------------------------------------------- BN+ReLU + transpose
__global__ __launch_bounds__(256) void bnT_kernel(
    const unsigned short* __restrict__ y2b, const float* __restrict__ ss,
    float* __restrict__ out)
{
    const int z = blockIdx.z;
    const int t = z >> 3, b = z & 7;
    const int o0 = blockIdx.y * 64;
    const int n0 = blockIdx.x * 64;
    const int tid = threadIdx.x;
    __shared__ unsigned short tile[64][72];

    const unsigned short* src = y2b + ((size_t)t * M_ + (size_t)b * N_ + n0) * OC_ + o0;
#pragma unroll
    for (int it = 0; it < 2; ++it) {
        int u = it * 256 + tid;
        int m_l = u >> 3, o8 = (u & 7) * 8;
        *(ush8*)&tile[m_l][o8] = *(const ush8*)(src + (size_t)m_l * OC_ + o8);
    }
    __syncthreads();
#pragma unroll
    for (int it = 0; it < 4; ++it) {
        int v = it * 256 + tid;
        int o_l = v >> 4, n4 = (v & 15) * 4;
        int o = o0 + o_l;
        float sc = ss[1024 + t * 256 + o];
        float sh = ss[1536 + t * 256 + o];
        float4 w;
        w.x = fmaxf(0.f, fmaf(bf2f(tile[n4][o_l]),     sc, sh));
        w.y = fmaxf(0.f, fmaf(bf2f(tile[n4 + 1][o_l]), sc, sh));
        w.z = fmaxf(0.f, fmaf(bf2f(tile[n4 + 2][o_l]), sc, sh));
        w.w = fmaxf(0.f, fmaf(bf2f(tile[n4 + 3][o_l]), sc, sh));
        *(float4*)(out + (((size_t)t * B_ + b) * OC_ + o) * N_ + n0 + n4) = w;
    }
}

// ---------------------------------------------------------------- launch
extern "C" void kernel_launch(void* const* d_in, const int* in_sizes, int n_in,
                              void* d_out, int out_size, void* d_ws, size_t ws_size,
                              hipStream_t stream)
{
    const float* xyz1    = (const float*)d_in[0];
    const float* xyz2    = (const float*)d_in[1];
    const float* points1 = (const float*)d_in[2];
    const float* points2 = (const float*)d_in[3];
    const float* colors1 = (const float*)d_in[4];
    const float* colors2 = (const float*)d_in[5];
    const float* Wp1  = (const float*)d_in[6];
    const float* gp1  = (const float*)d_in[8];
    const float* bep1 = (const float*)d_in[9];
    const float* Wc1  = (const float*)d_in[10];
    const float* gc1  = (const float*)d_in[12];
    const float* bec1 = (const float*)d_in[13];
    const float* Wp2  = (const float*)d_in[14];
    const float* gp2  = (const float*)d_in[16];
    const float* bep2 = (const float*)d_in[17];
    const float* Wc2  = (const float*)d_in[18];
    const float* gc2  = (const float*)d_in[20];
    const float* bec2 = (const float*)d_in[21];
    // biases (d_in[7,11,15,19]) unused: constant channel shift cancels in BN.

    char* ws = (char*)d_ws;
    unsigned short* y2b  = (unsigned short*)(ws + 0);
    unsigned short* Xp   = (unsigned short*)(ws + 0);         // overlays y2b
    unsigned short* p2b  = (unsigned short*)(ws + 16777216);
    unsigned short* c2b  = (unsigned short*)(ws + 20971520);
    int*   idxw = (int*)  (ws + 25165824);
    float* wgtw = (float*)(ws + 25559040);
    unsigned short* Y1   = (unsigned short*)(ws + 33554432);
    unsigned short* Wb1  = (unsigned short*)(ws + 67108864);
    unsigned short* Wb2  = (unsigned short*)(ws + 67895296);
    float* psum = (float*)(ws + 68419584);
    float* psq  = (float*)(ws + 68681728);
    float* ssb  = (float*)(ws + 68943872);
    float* out  = (float*)d_out;

    dim3 tb(32, 8);
    transpose2b_kernel<<<dim3(32, 8, 8), tb, 0, stream>>>(points2, p2b);
    transpose2b_kernel<<<dim3(32, 8, 8), tb, 0, stream>>>(colors2, c2b);
    convw_kernel<<<320, 256, 0, stream>>>(Wp1, Wc1, Wp2, Wc2, Wb1, Wb2);
    top3_kernel<<<dim3(128, 8), 256, 0, stream>>>(xyz1, xyz2, idxw, wgtw);
    buildxA_kernel<<<dim3(64, 8, 2), 256, 0, stream>>>(points1, colors1, Xp);
    gemm1f_kernel<<<dim3(128, 2), 512, 0, stream>>>(Xp, p2b, c2b, idxw, wgtw,
                                                    Wb1, Y1, psum, psq);
    reduce_kernel<<<dim3(2, 4), 256, 0, stream>>>(psum, psq, gp1, bep1, gc1, bec1, ssb, 0);
    gemm2f_kernel<<<dim3(128, 2), 512, 0, stream>>>(Y1, Wb2, ssb, y2b, psum, psq);
    reduce_kernel<<<dim3(2, 4), 256, 0, stream>>>(psum, psq, gp2, bep2, gc2, bec2, ssb, 1024);
    bnT_kernel<<<dim3(64, 4, 16), 256, 0, stream>>>(y2b, ssb, out);
}

// Round 6
// 119.151 us; speedup vs baseline: 4.2779x; 1.1182x over previous
//
#include <hip/hip_runtime.h>
#include <cstdint>
#include <cstddef>

// PointNet++ FP, bf16-MFMA pipeline v5: fused front-end + XCD-aware gemm1.
// B=8, N=4096, S=1024, D1=128, D2=256, IN_C=384, MLP=[256,256], BN training.
//
//  front:  ONE kernel, block-role dispatch:
//            [0,1024)      top3 (8 lanes/query, branchless + shfl_xor merge)
//            [1024,3072)   transpose points2 -> p2b bf16 [B][S][256]
//            [3072,5120)   transpose colors2 -> c2b bf16
//            [5120,5440)   convw: W* -> bf16 [o][k]
//            [5440,6464)   buildxA: points1/colors1 -> Xp bf16 [2][32768][128]
//  gemm1f: 256m x 256c, 8 waves, LDS dbuf prefetch; 1-D grid 256 with
//          xcd = wg&7, t = xcd&1 (per-XCD L2 holds one gather tensor);
//          B k<128 from Xp (gload_lds), k>=128 gathered; Y1 bf16 + stats
//  reduce(0); gemm2f: B = relu(bn(Y1)); y2b bf16 + stats; reduce(1024)
//  bnT: LDS-transpose + relu(bn) -> d_out [t][b][o][n] fp32
//
// ws layout (bytes), total 68,952,064:
//   y2b @0 (33.5M) overlays: Xp@0 | p2b@16777216 | c2b@20971520
//     | idxw@25165824 | wgtw@25559040
//   Y1 @33554432 | Wb1 @67108864 | Wb2 @67895296
//   psum @68419584 | psq @68681728 | ssb @68943872

#define B_   8
#define N_   4096
#define S_   1024
#define D1_  128
#define D2_  256
#define INC_ 384
#define OC_  256
#define M_   (B_ * N_)

typedef __attribute__((ext_vector_type(8))) short sh8;
typedef __attribute__((ext_vector_type(4))) float f32x4;
typedef __attribute__((ext_vector_type(4))) unsigned short ush4;
typedef __attribute__((ext_vector_type(8))) unsigned short ush8;

__device__ __forceinline__ unsigned short bf16rne(float f) {
    union { float f; unsigned u; } v; v.f = f;
    return (unsigned short)((v.u + 0x7FFFu + ((v.u >> 16) & 1u)) >> 16);
}
__device__ __forceinline__ float bf2f(unsigned short h) {
    union { unsigned u; float f; } v; v.u = ((unsigned)h) << 16;
    return v.f;
}
__device__ __forceinline__ void gload16(const void* gsrc, void* lds) {
    __builtin_amdgcn_global_load_lds(
        (const __attribute__((address_space(1))) void*)gsrc,
        (__attribute__((address_space(3))) void*)lds, 16, 0, 0);
}

// ---------------------------------------------------------------- front
#define INS(pd, pi) { \
    bool l0 = (pd < d0) || (pd == d0 && pi < i0); \
    bool l1 = (pd < d1) || (pd == d1 && pi < i1); \
    bool l2 = (pd < d2) || (pd == d2 && pi < i2); \
    d2 = l1 ? d1 : (l2 ? pd : d2);  i2 = l1 ? i1 : (l2 ? pi : i2); \
    d1 = l0 ? d0 : (l1 ? pd : d1);  i1 = l0 ? i0 : (l1 ? pi : i1); \
    d0 = l0 ? pd : d0;              i0 = l0 ? pi : i0; \
}

__global__ __launch_bounds__(256) void front_kernel(
    const float* __restrict__ xyz1, const float* __restrict__ xyz2,
    const float* __restrict__ points1, const float* __restrict__ colors1,
    const float* __restrict__ points2, const float* __restrict__ colors2,
    const float* __restrict__ Wp1, const float* __restrict__ Wc1,
    const float* __restrict__ Wp2, const float* __restrict__ Wc2,
    int* __restrict__ idxo, float* __restrict__ wo,
    unsigned short* __restrict__ p2b, unsigned short* __restrict__ c2b,
    unsigned short* __restrict__ Wb1, unsigned short* __restrict__ Wb2,
    unsigned short* __restrict__ Xp)
{
    __shared__ __align__(16) char fsm[33792];
    const int bid = blockIdx.x;
    const int tid = threadIdx.x;

    if (bid < 1024) {
        // ---- top-3 NN (critical path first)
        float4* sc = (float4*)fsm;
        const int b = bid >> 7, qb = bid & 127;
        const float* x2 = xyz2 + (size_t)b * 3 * S_;
        for (int s = tid; s < S_; s += 256) {
            float xs = x2[s], ys = x2[S_ + s], zs = x2[2 * S_ + s];
            sc[s] = make_float4(xs, ys, zs, xs * xs + ys * ys + zs * zs);
        }
        __syncthreads();
        const int q = qb * 32 + (tid >> 3);
        const int sub = tid & 7;
        const float* x1 = xyz1 + (size_t)b * 3 * N_;
        const float xq = x1[q], yq = x1[N_ + q], zq = x1[2 * N_ + q];
        const float n1 = xq * xq + yq * yq + zq * zq;
        float d0 = 3.4e38f, d1 = 3.4e38f, d2 = 3.4e38f;
        int i0 = 0, i1 = 0, i2 = 0;
#pragma unroll 4
        for (int j = 0; j < 128; ++j) {
            int s = j * 8 + sub;
            float4 v = sc[s];
            float dot = xq * v.x + yq * v.y + zq * v.z;
            float d = (n1 - 2.0f * dot) + v.w;
            bool c0 = d < d0, c1 = d < d1, c2 = d < d2;
            d2 = c1 ? d1 : (c2 ? d : d2); i2 = c1 ? i1 : (c2 ? s : i2);
            d1 = c0 ? d0 : (c1 ? d : d1); i1 = c0 ? i0 : (c1 ? s : i1);
            d0 = c0 ? d : d0;             i0 = c0 ? s : i0;
        }
#pragma unroll
        for (int off = 1; off < 8; off <<= 1) {
            float pd0 = __shfl_xor(d0, off), pd1 = __shfl_xor(d1, off), pd2 = __shfl_xor(d2, off);
            int   pi0 = __shfl_xor(i0, off), pi1 = __shfl_xor(i1, off), pi2 = __shfl_xor(i2, off);
            INS(pd0, pi0) INS(pd1, pi1) INS(pd2, pi2)
        }
        if (sub == 0) {
            float r0 = 1.f / (d0 + 1e-8f);
            float r1 = 1.f / (d1 + 1e-8f);
            float r2 = 1.f / (d2 + 1e-8f);
            float rs = r0 + r1 + r2;
            int base = (b * N_ + q) * 3;
            idxo[base] = i0; idxo[base + 1] = i1; idxo[base + 2] = i2;
            wo[base] = r0 / rs; wo[base + 1] = r1 / rs; wo[base + 2] = r2 / rs;
        }
    } else if (bid < 5120) {
        // ---- transpose points2/colors2 -> bf16 [B][S][256]
        float (*tile)[33] = (float(*)[33])fsm;
        const int u = bid - 1024;
        const int which = u >> 11;                 // 0: points2, 1: colors2
        const int v = u & 2047;
        const int z = v >> 8, rem = v & 255;
        const int cx = rem & 31, ry = rem >> 5;
        const int tx = tid & 31, ty = tid >> 5;
        const float* s = (which ? colors2 : points2) + (size_t)z * D2_ * S_;
        unsigned short* d = (which ? c2b : p2b) + (size_t)z * S_ * D2_;
#pragma unroll
        for (int i = 0; i < 4; ++i)
            tile[ty + i * 8][tx] = s[(size_t)(ry * 32 + ty + i * 8) * S_ + cx * 32 + tx];
        __syncthreads();
#pragma unroll
        for (int i = 0; i < 4; ++i)
            d[(size_t)(cx * 32 + ty + i * 8) * D2_ + ry * 32 + tx] =
                bf16rne(tile[tx][ty + i * 8]);
    } else if (bid < 5440) {
        // ---- convw
        int e = ((bid - 5120) * 256 + tid) * 4;
        const float* src; unsigned short* dst; int off;
        if (e < 98304)       { src = Wp1; dst = Wb1;          off = e; }
        else if (e < 196608) { src = Wc1; dst = Wb1 + 98304;  off = e - 98304; }
        else if (e < 262144) { src = Wp2; dst = Wb2;          off = e - 196608; }
        else                 { src = Wc2; dst = Wb2 + 65536;  off = e - 262144; }
        float4 v = *(const float4*)(src + off);
        ush4 o; o[0] = bf16rne(v.x); o[1] = bf16rne(v.y); o[2] = bf16rne(v.z); o[3] = bf16rne(v.w);
        *(ush4*)(dst + off) = o;
    } else {
        // ---- buildxA: transpose points1/colors1 -> Xp bf16
        float (*tileA)[132] = (float(*)[132])fsm;
        const int u = bid - 5440;
        const int t = u >> 9, rem = u & 511;
        const int b = rem >> 6, n0 = (rem & 63) * 64;
        const float* x1 = t ? colors1 : points1;
#pragma unroll
        for (int it = 0; it < 8; ++it) {
            int fl4 = it * 256 + tid;
            int d = fl4 >> 4, nl = (fl4 & 15) * 4;
            float4 v = *(const float4*)(x1 + ((size_t)b * D1_ + d) * N_ + n0 + nl);
            tileA[nl][d] = v.x; tileA[nl + 1][d] = v.y;
            tileA[nl + 2][d] = v.z; tileA[nl + 3][d] = v.w;
        }
        __syncthreads();
        size_t mbase = (size_t)t * M_ + (size_t)b * N_ + n0;
#pragma unroll
        for (int it = 0; it < 4; ++it) {
            int e8 = it * 256 + tid;
            int r = e8 >> 4, dc = (e8 & 15) * 8;
            ush8 o;
#pragma unroll
            for (int j = 0; j < 8; ++j) o[j] = bf16rne(tileA[r][dc + j]);
            *(ush8*)(Xp + (mbase + r) * D1_ + dc) = o;
        }
    }
}

// ---------------------------------------------------------------- GEMM1 (prefetch dbuf)
// 1-D grid 256; xcd = wg&7, t = xcd&1 -> per-XCD L2 caches one gather tensor.
__global__ __launch_bounds__(512, 2) void gemm1f_kernel(
    const unsigned short* __restrict__ Xp,
    const unsigned short* __restrict__ p2b,
    const unsigned short* __restrict__ c2b,
    const int* __restrict__ idxw, const float* __restrict__ wgtw,
    const unsigned short* __restrict__ Wb1,
    unsigned short* __restrict__ Y1,
    float* __restrict__ psum, float* __restrict__ psq)
{
    const int wg  = blockIdx.x;
    const int xcd = wg & 7;
    const int t   = xcd & 1;
    const int mt  = (xcd >> 1) * 32 + (wg >> 3);   // 0..127, bijective
    const int m0  = mt * 256;
    const int bb  = m0 >> 12;
    const unsigned short* Aw  = Wb1 + (size_t)t * (OC_ * INC_);
    const unsigned short* Xb  = Xp + (size_t)t * M_ * D1_;
    const unsigned short* f2b = t ? c2b : p2b;

    __shared__ __align__(16) char smem[131072];

    const int tid  = threadIdx.x;
    const int lane = tid & 63;
    const int wid  = tid >> 6;
    const int wc   = wid & 3;
    const int wm   = wid >> 2;
    const int srow = tid >> 3;
    const int k8   = (tid & 7) * 8;
    const int sk   = ((tid & 7) ^ (srow & 7)) * 8;
    const int kgrp = (lane >> 4) * 16;

    int gi[4][3]; float gw[4][3];
#pragma unroll
    for (int p = 0; p < 4; ++p) {
        int base = (m0 + p * 64 + srow) * 3;
#pragma unroll
        for (int j = 0; j < 3; ++j) { gi[p][j] = idxw[base + j]; gw[p][j] = wgtw[base + j]; }
    }

    f32x4 acc[4][8];
#pragma unroll
    for (int i = 0; i < 4; ++i)
#pragma unroll
        for (int j = 0; j < 8; ++j) acc[i][j] = f32x4{0.f, 0.f, 0.f, 0.f};

    auto stageA = [&](int buf, int kc) {
#pragma unroll
        for (int p = 0; p < 4; ++p)
            gload16(Aw + (size_t)(p * 64 + srow) * INC_ + kc + sk,
                    smem + buf * 32768 + p * 8192 + wid * 1024);
    };
    auto stageBX = [&](int buf, int kc) {
#pragma unroll
        for (int p = 0; p < 4; ++p)
            gload16(Xb + (size_t)(m0 + p * 64 + srow) * D1_ + kc + sk,
                    smem + 65536 + buf * 32768 + p * 8192 + wid * 1024);
    };
    auto stageBG = [&](int buf, int kc) {
        const int d0k = kc - D1_ + k8;
#pragma unroll
        for (int p = 0; p < 4; ++p) {
            int row = p * 64 + srow;
            ush8 a0 = *(const ush8*)(f2b + ((size_t)bb * S_ + gi[p][0]) * D2_ + d0k);
            ush8 a1 = *(const ush8*)(f2b + ((size_t)bb * S_ + gi[p][1]) * D2_ + d0k);
            ush8 a2 = *(const ush8*)(f2b + ((size_t)bb * S_ + gi[p][2]) * D2_ + d0k);
            ush8 ov;
#pragma unroll
            for (int j = 0; j < 8; ++j)
                ov[j] = bf16rne(gw[p][0] * bf2f(a0[j]) + gw[p][1] * bf2f(a1[j])
                              + gw[p][2] * bf2f(a2[j]));
            *(ush8*)(smem + 65536 + buf * 32768 + row * 128
                     + ((k8 * 2) ^ ((row & 7) << 4))) = ov;
        }
    };
    auto compute = [&](int buf) {
#pragma unroll
        for (int kk = 0; kk < 2; ++kk) {
            sh8 a[4], b[8];
#pragma unroll
            for (int f = 0; f < 4; ++f) {
                int ra = wc * 64 + (lane & 15) + f * 16;
                a[f] = *(const sh8*)(smem + buf * 32768 + ra * 128
                        + ((kk * 64 + kgrp) ^ ((ra & 7) << 4)));
            }
#pragma unroll
            for (int f = 0; f < 8; ++f) {
                int rb = wm * 128 + (lane & 15) + f * 16;
                b[f] = *(const sh8*)(smem + 65536 + buf * 32768 + rb * 128
                        + ((kk * 64 + kgrp) ^ ((rb & 7) << 4)));
            }
#pragma unroll
            for (int fc = 0; fc < 4; ++fc)
#pragma unroll
                for (int fm = 0; fm < 8; ++fm)
                    acc[fc][fm] = __builtin_amdgcn_mfma_f32_16x16x32_bf16(
                        a[fc], b[fm], acc[fc][fm], 0, 0, 0);
        }
    };

    stageA(0, 0); stageBX(0, 0);
    __syncthreads();
    int cur = 0;
    for (int step = 0; step < 6; ++step) {
        int kcn = (step + 1) * 64;
        if (step < 5) {
            stageA(cur ^ 1, kcn);
            if (kcn < D1_) stageBX(cur ^ 1, kcn);
            else           stageBG(cur ^ 1, kcn);
        }
        compute(cur);
        __syncthreads();
        cur ^= 1;
    }

    const int mrow = m0 + wm * 128 + (lane & 15);
    const int chq  = (lane >> 4) * 4;
#pragma unroll
    for (int fm = 0; fm < 8; ++fm)
#pragma unroll
        for (int fc = 0; fc < 4; ++fc) {
            ush4 v;
#pragma unroll
            for (int r = 0; r < 4; ++r) v[r] = bf16rne(acc[fc][fm][r]);
            *(ush4*)(Y1 + ((size_t)t * M_ + mrow + fm * 16) * OC_
                      + wc * 64 + fc * 16 + chq) = v;
        }

    float* sArr = (float*)smem;
    const int contrib = wm * 16 + (lane & 15);
#pragma unroll
    for (int ph = 0; ph < 2; ++ph) {
#pragma unroll
        for (int fc = 0; fc < 4; ++fc) {
            f32x4 s4;
#pragma unroll
            for (int r = 0; r < 4; ++r) {
                float s = 0.f;
#pragma unroll
                for (int fm = 0; fm < 8; ++fm) { float v = acc[fc][fm][r]; s += ph ? v * v : v; }
                s4[r] = s;
            }
            *(f32x4*)&sArr[contrib * 264 + wc * 64 + fc * 16 + chq] = s4;
        }
        __syncthreads();
        if (tid < 256) {
            float s = 0.f;
#pragma unroll
            for (int k = 0; k < 32; ++k) s += sArr[((k + tid) & 31) * 264 + tid];
            (ph ? psq : psum)[((size_t)t * 128 + mt) * 256 + tid] = s;
        }
        __syncthreads();
    }
}

// ---------------------------------------------------------------- stats reduce
__global__ __launch_bounds__(256) void reduce_kernel(
    const float* __restrict__ psum, const float* __restrict__ psq,
    const float* __restrict__ gp, const float* __restrict__ bep,
    const float* __restrict__ gc, const float* __restrict__ bec,
    float* __restrict__ ss, int layerOff)
{
    const int t = blockIdx.x, cs = blockIdx.y;
    const int tid = threadIdx.x;
    const int cl = tid & 63, grp = tid >> 6;
    const int c = cs * 64 + cl;
    float s = 0.f, q = 0.f;
    for (int k = grp; k < 128; k += 4) {
        s += psum[((size_t)t * 128 + k) * 256 + c];
        q += psq [((size_t)t * 128 + k) * 256 + c];
    }
    __shared__ float ls[4][64], lq[4][64];
    ls[grp][cl] = s; lq[grp][cl] = q;
    __syncthreads();
    if (tid < 64) {
        s = ls[0][cl] + ls[1][cl] + ls[2][cl] + ls[3][cl];
        q = lq[0][cl] + lq[1][cl] + lq[2][cl] + lq[3][cl];
        float mean = s * (1.f / (float)M_);
        float var  = q * (1.f / (float)M_) - mean * mean;
        float inv  = rsqrtf(var + 1e-5f);
        float g = (t ? gc : gp)[c], be = (t ? bec : bep)[c];
        float sc = g * inv;
        ss[layerOff + t * 256 + c]       = sc;
        ss[layerOff + 512 + t * 256 + c] = be - mean * sc;
    }
}

// ---------------------------------------------------------------- GEMM2 (prefetch dbuf)
__global__ __launch_bounds__(512, 2) void gemm2f_kernel(
    const unsigned short* __restrict__ Y1,
    const unsigned short* __restrict__ Wb2,
    const float* __restrict__ ss,
    unsigned short* __restrict__ y2b,
    float* __restrict__ psum, float* __restrict__ psq)
{
    const int t  = blockIdx.y;
    const int m0 = blockIdx.x * 256;
    const unsigned short* Aw = Wb2 + (size_t)t * (OC_ * OC_);
    const unsigned short* By = Y1 + (size_t)t * M_ * OC_;

    __shared__ __align__(16) char smem[131072];
    __shared__ float Slds[256], Hlds[256];

    const int tid  = threadIdx.x;
    const int lane = tid & 63;
    const int wid  = tid >> 6;
    const int wc   = wid & 3;
    const int wm   = wid >> 2;
    const int srow = tid >> 3;
    const int k8   = (tid & 7) * 8;
    const int sk   = ((tid & 7) ^ (srow & 7)) * 8;
    const int kgrp = (lane >> 4) * 16;

    if (tid < 256) { Slds[tid] = ss[t * 256 + tid]; Hlds[tid] = ss[512 + t * 256 + tid]; }
    __syncthreads();

    f32x4 acc[4][8];
#pragma unroll
    for (int i = 0; i < 4; ++i)
#pragma unroll
        for (int j = 0; j < 8; ++j) acc[i][j] = f32x4{0.f, 0.f, 0.f, 0.f};

    auto stageA = [&](int buf, int kc) {
#pragma unroll
        for (int p = 0; p < 4; ++p)
            gload16(Aw + (size_t)(p * 64 + srow) * OC_ + kc + sk,
                    smem + buf * 32768 + p * 8192 + wid * 1024);
    };
    auto stageBY = [&](int buf, int kc) {
#pragma unroll
        for (int p = 0; p < 4; ++p) {
            int row = p * 64 + srow;
            ush8 yv = *(const ush8*)(By + (size_t)(m0 + row) * OC_ + kc + k8);
            ush8 ov;
#pragma unroll
            for (int j = 0; j < 8; ++j) {
                float y = bf2f(yv[j]);
                ov[j] = bf16rne(fmaxf(0.f, fmaf(y, Slds[kc + k8 + j], Hlds[kc + k8 + j])));
            }
            *(ush8*)(smem + 65536 + buf * 32768 + row * 128
                     + ((k8 * 2) ^ ((row & 7) << 4))) = ov;
        }
    };
    auto compute = [&](int buf) {
#pragma unroll
        for (int kk = 0; kk < 2; ++kk) {
            sh8 a[4], b[8];
#pragma unroll
            for (int f = 0; f < 4; ++f) {
                int ra = wc * 64 + (lane & 15) + f * 16;
                a[f] = *(const sh8*)(smem + buf * 32768 + ra * 128
                        + ((kk * 64 + kgrp) ^ ((ra & 7) << 4)));
            }
#pragma unroll
            for (int f = 0; f < 8; ++f) {
                int rb = wm * 128 + (lane & 15) + f * 16;
                b[f] = *(const sh8*)(smem + 65536 + buf * 32768 + rb * 128
                        + ((kk * 64 + kgrp) ^ ((rb & 7) << 4)));
            }
#pragma unroll
            for (int fc = 0; fc < 4; ++fc)
#pragma unroll
                for (int fm = 0; fm < 8; ++fm)
                    acc[fc][fm] = __builtin_amdgcn_mfma_f32_16x16x32_bf16(
                        a[fc], b[fm], acc[fc][fm], 0, 0, 0);
        }
    };

    stageA(0, 0); stageBY(0, 0);
    __syncthreads();
    int cur = 0;
    for (int step = 0; step < 4; ++step) {
        int kcn = (step + 1) * 64;
        if (step < 3) { stageA(cur ^ 1, kcn); stageBY(cur ^ 1, kcn); }
        compute(cur);
        __syncthreads();
        cur ^= 1;
    }

    const int mrow = m0 + wm * 128 + (lane & 15);
    const int chq  = (lane >> 4) * 4;
#pragma unroll
    for (int fm = 0; fm < 8; ++fm)
#pragma unroll
        for (int fc = 0; fc < 4; ++fc) {
            ush4 v;
#pragma unroll
            for (int r = 0; r < 4; ++r) v[r] = bf16rne(acc[fc][fm][r]);
            *(ush4*)(y2b + ((size_t)t * M_ + mrow + fm * 16) * OC_
                      + wc * 64 + fc * 16 + chq) = v;
        }

    float* sArr = (float*)smem;
    const int contrib = wm * 16 + (lane & 15);
#pragma unroll
    for (int ph = 0; ph < 2; ++ph) {
#pragma unroll
        for (int fc = 0; fc < 4; ++fc) {
            f32x4 s4;
#pragma unroll
            for (int r = 0; r < 4; ++r) {
                float s = 0.f;
#pragma unroll
                for (int fm = 0; fm < 8; ++fm) { float v = acc[fc][fm][r]; s += ph ? v * v : v; }
                s4[r] = s;
            }
            *(f32x4*)&sArr[contrib * 264 + wc * 64 + fc * 16 + chq] = s4;
        }
        __syncthreads();
        if (tid < 256) {
            float s = 0.f;
#pragma unroll
            for (int k = 0; k < 32; ++k) s += sArr[((k + tid) & 31) * 264 + tid];
            (ph ? psq : psum)[((size_t)t * 128 + blockIdx.x) * 256 + tid] = s;
        }
        __syncthreads();
    }
}

// ---------------------------------------------------------------- BN+ReLU + transpose
__global__ __launch_bounds__(256) void bnT_kernel(
    const unsigned short* __restrict__ y2b, const float* __restrict__ ss,
    float* __restrict__ out)
{
    const int z = blockIdx.z;
    const int t = z >> 3, b = z & 7;
    const int o0 = blockIdx.y * 64;
    const int n0 = blockIdx.x * 64;
    const int tid = threadIdx.x;
    __shared__ unsigned short tile[64][72];

    const unsigned short* src = y2b + ((size_t)t * M_ + (size_t)b * N_ + n0) * OC_ + o0;
#pragma unroll
    for (int it = 0; it < 2; ++it) {
        int u = it * 256 + tid;
        int m_l = u >> 3, o8 = (u & 7) * 8;
        *(ush8*)&tile[m_l][o8] = *(const ush8*)(src + (size_t)m_l * OC_ + o8);
    }
    __syncthreads();
#pragma unroll
    for (int it = 0; it < 4; ++it) {
        int v = it * 256 + tid;
        int o_l = v >> 4, n4 = (v & 15) * 4;
        int o = o0 + o_l;
        float sc = ss[1024 + t * 256 + o];
        float sh = ss[1536 + t * 256 + o];
        float4 w;
        w.x = fmaxf(0.f, fmaf(bf2f(tile[n4][o_l]),     sc, sh));
        w.y = fmaxf(0.f, fmaf(bf2f(tile[n4 + 1][o_l]), sc, sh));
        w.z = fmaxf(0.f, fmaf(bf2f(tile[n4 + 2][o_l]), sc, sh));
        w.w = fmaxf(0.f, fmaf(bf2f(tile[n4 + 3][o_l]), sc, sh));
        *(float4*)(out + (((size_t)t * B_ + b) * OC_ + o) * N_ + n0 + n4) = w;
    }
}

// ---------------------------------------------------------------- launch
extern "C" void kernel_launch(void* const* d_in, const int* in_sizes, int n_in,
                              void* d_out, int out_size, void* d_ws, size_t ws_size,
                              hipStream_t stream)
{
    const float* xyz1    = (const float*)d_in[0];
    const float* xyz2    = (const float*)d_in[1];
    const float* points1 = (const float*)d_in[2];
    const float* points2 = (const float*)d_in[3];
    const float* colors1 = (const float*)d_in[4];
    const float* colors2 = (const float*)d_in[5];
    const float* Wp1  = (const float*)d_in[6];
    const float* gp1  = (const float*)d_in[8];
    const float* bep1 = (const float*)d_in[9];
    const float* Wc1  = (const float*)d_in[10];
    const float* gc1  = (const float*)d_in[12];
    const float* bec1 = (const float*)d_in[13];
    const float* Wp2  = (const float*)d_in[14];
    const float* gp2  = (const float*)d_in[16];
    const float* bep2 = (const float*)d_in[17];
    const float* Wc2  = (const float*)d_in[18];
    const float* gc2  = (const float*)d_in[20];
    const float* bec2 = (const float*)d_in[21];
    // biases (d_in[7,11,15,19]) unused: constant channel shift cancels in BN.

    char* ws = (char*)d_ws;
    unsigned short* y2b  = (unsigned short*)(ws + 0);
    unsigned short* Xp   = (unsigned short*)(ws + 0);         // overlays y2b
    unsigned short* p2b  = (unsigned short*)(ws + 16777216);
    unsigned short* c2b  = (unsigned short*)(ws + 20971520);
    int*   idxw = (int*)  (ws + 25165824);
    float* wgtw = (float*)(ws + 25559040);
    unsigned short* Y1   = (unsigned short*)(ws + 33554432);
    unsigned short* Wb1  = (unsigned short*)(ws + 67108864);
    unsigned short* Wb2  = (unsigned short*)(ws + 67895296);
    float* psum = (float*)(ws + 68419584);
    float* psq  = (float*)(ws + 68681728);
    float* ssb  = (float*)(ws + 68943872);
    float* out  = (float*)d_out;

    front_kernel<<<6464, 256, 0, stream>>>(xyz1, xyz2, points1, colors1,
                                           points2, colors2, Wp1, Wc1, Wp2, Wc2,
                                           idxw, wgtw, p2b, c2b, Wb1, Wb2, Xp);
    gemm1f_kernel<<<256, 512, 0, stream>>>(Xp, p2b, c2b, idxw, wgtw,
                                           Wb1, Y1, psum, psq);
    reduce_kernel<<<dim3(2, 4), 256, 0, stream>>>(psum, psq, gp1, bep1, gc1, bec1, ssb, 0);
    gemm2f_kernel<<<dim3(128, 2), 512, 0, stream>>>(Y1, Wb2, ssb, y2b, psum, psq);
    reduce_kernel<<<dim3(2, 4), 256, 0, stream>>>(psum, psq, gp2, bep2, gc2, bec2, ssb, 1024);
    bnT_kernel<<<dim3(64, 4, 16), 256, 0, stream>>>(y2b, ssb, out);
}

// Round 7
// 113.757 us; speedup vs baseline: 4.4807x; 1.0474x over previous
//
#include <hip/hip_runtime.h>
#include <cstdint>
#include <cstddef>

// PointNet++ FP, bf16-MFMA pipeline v6: occupancy-slim front.
// B=8, N=4096, S=1024, D1=128, D2=256, IN_C=384, MLP=[256,256], BN training.
//
//  front:  ONE kernel (17.7 KB LDS -> 8 blocks/CU), block-role dispatch:
//            [0,1024)      top3 (8 lanes/query, branchless + shfl_xor merge)
//            [1024,3072)   transpose points2 -> p2b bf16 [B][S][256]
//            [3072,5120)   transpose colors2 -> c2b bf16
//            [5120,5440)   convw: W* -> bf16 [o][k]
//            [5440,6464)   buildxA: points1/colors1 -> Xp bf16 (2-phase, 69-pad)
//  gemm1f: 256m x 256c, 8 waves, LDS dbuf prefetch; xcd=wg&7, t=xcd&1
//  reduce(0); gemm2f: B = relu(bn(Y1)); y2b bf16 + stats; reduce(1024)
//  bnT: LDS-transpose + relu(bn) -> d_out [t][b][o][n] fp32
//
// ws layout (bytes), total 68,952,064:
//   y2b @0 (33.5M) overlays: Xp@0 | p2b@16777216 | c2b@20971520
//     | idxw@25165824 | wgtw@25559040
//   Y1 @33554432 | Wb1 @67108864 | Wb2 @67895296
//   psum @68419584 | psq @68681728 | ssb @68943872

#define B_   8
#define N_   4096
#define S_   1024
#define D1_  128
#define D2_  256
#define INC_ 384
#define OC_  256
#define M_   (B_ * N_)

typedef __attribute__((ext_vector_type(8))) short sh8;
typedef __attribute__((ext_vector_type(4))) float f32x4;
typedef __attribute__((ext_vector_type(4))) unsigned short ush4;
typedef __attribute__((ext_vector_type(8))) unsigned short ush8;

__device__ __forceinline__ unsigned short bf16rne(float f) {
    union { float f; unsigned u; } v; v.f = f;
    return (unsigned short)((v.u + 0x7FFFu + ((v.u >> 16) & 1u)) >> 16);
}
__device__ __forceinline__ float bf2f(unsigned short h) {
    union { unsigned u; float f; } v; v.u = ((unsigned)h) << 16;
    return v.f;
}
__device__ __forceinline__ void gload16(const void* gsrc, void* lds) {
    __builtin_amdgcn_global_load_lds(
        (const __attribute__((address_space(1))) void*)gsrc,
        (__attribute__((address_space(3))) void*)lds, 16, 0, 0);
}

// ---------------------------------------------------------------- front
#define INS(pd, pi) { \
    bool l0 = (pd < d0) || (pd == d0 && pi < i0); \
    bool l1 = (pd < d1) || (pd == d1 && pi < i1); \
    bool l2 = (pd < d2) || (pd == d2 && pi < i2); \
    d2 = l1 ? d1 : (l2 ? pd : d2);  i2 = l1 ? i1 : (l2 ? pi : i2); \
    d1 = l0 ? d0 : (l1 ? pd : d1);  i1 = l0 ? i0 : (l1 ? pi : i1); \
    d0 = l0 ? pd : d0;              i0 = l0 ? pi : i0; \
}

__global__ __launch_bounds__(256) void front_kernel(
    const float* __restrict__ xyz1, const float* __restrict__ xyz2,
    const float* __restrict__ points1, const float* __restrict__ colors1,
    const float* __restrict__ points2, const float* __restrict__ colors2,
    const float* __restrict__ Wp1, const float* __restrict__ Wc1,
    const float* __restrict__ Wp2, const float* __restrict__ Wc2,
    int* __restrict__ idxo, float* __restrict__ wo,
    unsigned short* __restrict__ p2b, unsigned short* __restrict__ c2b,
    unsigned short* __restrict__ Wb1, unsigned short* __restrict__ Wb2,
    unsigned short* __restrict__ Xp)
{
    __shared__ __align__(16) char fsm[17664];   // max(top3 16K, tileA 64*69*4)
    const int bid = blockIdx.x;
    const int tid = threadIdx.x;

    if (bid < 1024) {
        // ---- top-3 NN (critical path first)
        float4* sc = (float4*)fsm;
        const int b = bid >> 7, qb = bid & 127;
        const float* x2 = xyz2 + (size_t)b * 3 * S_;
        for (int s = tid; s < S_; s += 256) {
            float xs = x2[s], ys = x2[S_ + s], zs = x2[2 * S_ + s];
            sc[s] = make_float4(xs, ys, zs, xs * xs + ys * ys + zs * zs);
        }
        __syncthreads();
        const int q = qb * 32 + (tid >> 3);
        const int sub = tid & 7;
        const float* x1 = xyz1 + (size_t)b * 3 * N_;
        const float xq = x1[q], yq = x1[N_ + q], zq = x1[2 * N_ + q];
        const float n1 = xq * xq + yq * yq + zq * zq;
        float d0 = 3.4e38f, d1 = 3.4e38f, d2 = 3.4e38f;
        int i0 = 0, i1 = 0, i2 = 0;
#pragma unroll 4
        for (int j = 0; j < 128; ++j) {
            int s = j * 8 + sub;
            float4 v = sc[s];
            float dot = xq * v.x + yq * v.y + zq * v.z;
            float d = (n1 - 2.0f * dot) + v.w;
            bool c0 = d < d0, c1 = d < d1, c2 = d < d2;
            d2 = c1 ? d1 : (c2 ? d : d2); i2 = c1 ? i1 : (c2 ? s : i2);
            d1 = c0 ? d0 : (c1 ? d : d1); i1 = c0 ? i0 : (c1 ? s : i1);
            d0 = c0 ? d : d0;             i0 = c0 ? s : i0;
        }
#pragma unroll
        for (int off = 1; off < 8; off <<= 1) {
            float pd0 = __shfl_xor(d0, off), pd1 = __shfl_xor(d1, off), pd2 = __shfl_xor(d2, off);
            int   pi0 = __shfl_xor(i0, off), pi1 = __shfl_xor(i1, off), pi2 = __shfl_xor(i2, off);
            INS(pd0, pi0) INS(pd1, pi1) INS(pd2, pi2)
        }
        if (sub == 0) {
            float r0 = 1.f / (d0 + 1e-8f);
            float r1 = 1.f / (d1 + 1e-8f);
            float r2 = 1.f / (d2 + 1e-8f);
            float rs = r0 + r1 + r2;
            int base = (b * N_ + q) * 3;
            idxo[base] = i0; idxo[base + 1] = i1; idxo[base + 2] = i2;
            wo[base] = r0 / rs; wo[base + 1] = r1 / rs; wo[base + 2] = r2 / rs;
        }
    } else if (bid < 5120) {
        // ---- transpose points2/colors2 -> bf16 [B][S][256]
        float (*tile)[33] = (float(*)[33])fsm;
        const int u = bid - 1024;
        const int which = u >> 11;                 // 0: points2, 1: colors2
        const int v = u & 2047;
        const int z = v >> 8, rem = v & 255;
        const int cx = rem & 31, ry = rem >> 5;
        const int tx = tid & 31, ty = tid >> 5;
        const float* s = (which ? colors2 : points2) + (size_t)z * D2_ * S_;
        unsigned short* d = (which ? c2b : p2b) + (size_t)z * S_ * D2_;
#pragma unroll
        for (int i = 0; i < 4; ++i)
            tile[ty + i * 8][tx] = s[(size_t)(ry * 32 + ty + i * 8) * S_ + cx * 32 + tx];
        __syncthreads();
#pragma unroll
        for (int i = 0; i < 4; ++i)
            d[(size_t)(cx * 32 + ty + i * 8) * D2_ + ry * 32 + tx] =
                bf16rne(tile[tx][ty + i * 8]);
    } else if (bid < 5440) {
        // ---- convw
        int e = ((bid - 5120) * 256 + tid) * 4;
        const float* src; unsigned short* dst; int off;
        if (e < 98304)       { src = Wp1; dst = Wb1;          off = e; }
        else if (e < 196608) { src = Wc1; dst = Wb1 + 98304;  off = e - 98304; }
        else if (e < 262144) { src = Wp2; dst = Wb2;          off = e - 196608; }
        else                 { src = Wc2; dst = Wb2 + 65536;  off = e - 262144; }
        float4 v = *(const float4*)(src + off);
        ush4 o; o[0] = bf16rne(v.x); o[1] = bf16rne(v.y); o[2] = bf16rne(v.z); o[3] = bf16rne(v.w);
        *(ush4*)(dst + off) = o;
    } else {
        // ---- buildxA: transpose points1/colors1 -> Xp bf16, 2-phase (64 d each)
        float (*tileA)[69] = (float(*)[69])fsm;
        const int u = bid - 5440;
        const int t = u >> 9, rem = u & 511;
        const int b = rem >> 6, n0 = (rem & 63) * 64;
        const float* x1 = t ? colors1 : points1;
        size_t mbase = (size_t)t * M_ + (size_t)b * N_ + n0;
#pragma unroll
        for (int ph = 0; ph < 2; ++ph) {
            if (ph) __syncthreads();
#pragma unroll
            for (int it = 0; it < 4; ++it) {
                int fl4 = it * 256 + tid;
                int dl = fl4 >> 4, nl = (fl4 & 15) * 4;
                float4 v = *(const float4*)(x1 + ((size_t)b * D1_ + ph * 64 + dl) * N_ + n0 + nl);
                tileA[nl][dl] = v.x; tileA[nl + 1][dl] = v.y;
                tileA[nl + 2][dl] = v.z; tileA[nl + 3][dl] = v.w;
            }
            __syncthreads();
#pragma unroll
            for (int it = 0; it < 2; ++it) {
                int e8 = it * 256 + tid;
                int r = e8 >> 3, dc = (e8 & 7) * 8;
                ush8 o;
#pragma unroll
                for (int j = 0; j < 8; ++j) o[j] = bf16rne(tileA[r][dc + j]);
                *(ush8*)(Xp + (mbase + r) * D1_ + ph * 64 + dc) = o;
            }
        }
    }
}

// ---------------------------------------------------------------- GEMM1 (prefetch dbuf)
// 1-D grid 256; xcd = wg&7, t = xcd&1 -> per-XCD L2 caches one gather tensor.
__global__ __launch_bounds__(512, 2) void gemm1f_kernel(
    const unsigned short* __restrict__ Xp,
    const unsigned short* __restrict__ p2b,
    const unsigned short* __restrict__ c2b,
    const int* __restrict__ idxw, const float* __restrict__ wgtw,
    const unsigned short* __restrict__ Wb1,
    unsigned short* __restrict__ Y1,
    float* __restrict__ psum, float* __restrict__ psq)
{
    const int wg  = blockIdx.x;
    const int xcd = wg & 7;
    const int t   = xcd & 1;
    const int mt  = (xcd >> 1) * 32 + (wg >> 3);   // 0..127, bijective
    const int m0  = mt * 256;
    const int bb  = m0 >> 12;
    const unsigned short* Aw  = Wb1 + (size_t)t * (OC_ * INC_);
    const unsigned short* Xb  = Xp + (size_t)t * M_ * D1_;
    const unsigned short* f2b = t ? c2b : p2b;

    __shared__ __align__(16) char smem[131072];

    const int tid  = threadIdx.x;
    const int lane = tid & 63;
    const int wid  = tid >> 6;
    const int wc   = wid & 3;
    const int wm   = wid >> 2;
    const int srow = tid >> 3;
    const int k8   = (tid & 7) * 8;
    const int sk   = ((tid & 7) ^ (srow & 7)) * 8;
    const int kgrp = (lane >> 4) * 16;

    int gi[4][3]; float gw[4][3];
#pragma unroll
    for (int p = 0; p < 4; ++p) {
        int base = (m0 + p * 64 + srow) * 3;
#pragma unroll
        for (int j = 0; j < 3; ++j) { gi[p][j] = idxw[base + j]; gw[p][j] = wgtw[base + j]; }
    }

    f32x4 acc[4][8];
#pragma unroll
    for (int i = 0; i < 4; ++i)
#pragma unroll
        for (int j = 0; j < 8; ++j) acc[i][j] = f32x4{0.f, 0.f, 0.f, 0.f};

    auto stageA = [&](int buf, int kc) {
#pragma unroll
        for (int p = 0; p < 4; ++p)
            gload16(Aw + (size_t)(p * 64 + srow) * INC_ + kc + sk,
                    smem + buf * 32768 + p * 8192 + wid * 1024);
    };
    auto stageBX = [&](int buf, int kc) {
#pragma unroll
        for (int p = 0; p < 4; ++p)
            gload16(Xb + (size_t)(m0 + p * 64 + srow) * D1_ + kc + sk,
                    smem + 65536 + buf * 32768 + p * 8192 + wid * 1024);
    };
    auto stageBG = [&](int buf, int kc) {
        const int d0k = kc - D1_ + k8;
#pragma unroll
        for (int p = 0; p < 4; ++p) {
            int row = p * 64 + srow;
            ush8 a0 = *(const ush8*)(f2b + ((size_t)bb * S_ + gi[p][0]) * D2_ + d0k);
            ush8 a1 = *(const ush8*)(f2b + ((size_t)bb * S_ + gi[p][1]) * D2_ + d0k);
            ush8 a2 = *(const ush8*)(f2b + ((size_t)bb * S_ + gi[p][2]) * D2_ + d0k);
            ush8 ov;
#pragma unroll
            for (int j = 0; j < 8; ++j)
                ov[j] = bf16rne(gw[p][0] * bf2f(a0[j]) + gw[p][1] * bf2f(a1[j])
                              + gw[p][2] * bf2f(a2[j]));
            *(ush8*)(smem + 65536 + buf * 32768 + row * 128
                     + ((k8 * 2) ^ ((row & 7) << 4))) = ov;
        }
    };
    auto compute = [&](int buf) {
#pragma unroll
        for (int kk = 0; kk < 2; ++kk) {
            sh8 a[4], b[8];
#pragma unroll
            for (int f = 0; f < 4; ++f) {
                int ra = wc * 64 + (lane & 15) + f * 16;
                a[f] = *(const sh8*)(smem + buf * 32768 + ra * 128
                        + ((kk * 64 + kgrp) ^ ((ra & 7) << 4)));
            }
#pragma unroll
            for (int f = 0; f < 8; ++f) {
                int rb = wm * 128 + (lane & 15) + f * 16;
                b[f] = *(const sh8*)(smem + 65536 + buf * 32768 + rb * 128
                        + ((kk * 64 + kgrp) ^ ((rb & 7) << 4)));
            }
#pragma unroll
            for (int fc = 0; fc < 4; ++fc)
#pragma unroll
                for (int fm = 0; fm < 8; ++fm)
                    acc[fc][fm] = __builtin_amdgcn_mfma_f32_16x16x32_bf16(
                        a[fc], b[fm], acc[fc][fm], 0, 0, 0);
        }
    };

    stageA(0, 0); stageBX(0, 0);
    __syncthreads();
    int cur = 0;
    for (int step = 0; step < 6; ++step) {
        int kcn = (step + 1) * 64;
        if (step < 5) {
            stageA(cur ^ 1, kcn);
            if (kcn < D1_) stageBX(cur ^ 1, kcn);
            else           stageBG(cur ^ 1, kcn);
        }
        compute(cur);
        __syncthreads();
        cur ^= 1;
    }

    const int mrow = m0 + wm * 128 + (lane & 15);
    const int chq  = (lane >> 4) * 4;
#pragma unroll
    for (int fm = 0; fm < 8; ++fm)
#pragma unroll
        for (int fc = 0; fc < 4; ++fc) {
            ush4 v;
#pragma unroll
            for (int r = 0; r < 4; ++r) v[r] = bf16rne(acc[fc][fm][r]);
            *(ush4*)(Y1 + ((size_t)t * M_ + mrow + fm * 16) * OC_
                      + wc * 64 + fc * 16 + chq) = v;
        }

    float* sArr = (float*)smem;
    const int contrib = wm * 16 + (lane & 15);
#pragma unroll
    for (int ph = 0; ph < 2; ++ph) {
#pragma unroll
        for (int fc = 0; fc < 4; ++fc) {
            f32x4 s4;
#pragma unroll
            for (int r = 0; r < 4; ++r) {
                float s = 0.f;
#pragma unroll
                for (int fm = 0; fm < 8; ++fm) { float v = acc[fc][fm][r]; s += ph ? v * v : v; }
                s4[r] = s;
            }
            *(f32x4*)&sArr[contrib * 264 + wc * 64 + fc * 16 + chq] = s4;
        }
        __syncthreads();
        if (tid < 256) {
            float s = 0.f;
#pragma unroll
            for (int k = 0; k < 32; ++k) s += sArr[((k + tid) & 31) * 264 + tid];
            (ph ? psq : psum)[((size_t)t * 128 + mt) * 256 + tid] = s;
        }
        __syncthreads();
    }
}

// ---------------------------------------------------------------- stats reduce
__global__ __launch_bounds__(256) void reduce_kernel(
    const float* __restrict__ psum, const float* __restrict__ psq,
    const float* __restrict__ gp, const float* __restrict__ bep,
    const float* __restrict__ gc, const float* __restrict__ bec,
    float* __restrict__ ss, int layerOff)
{
    const int t = blockIdx.x, cs = blockIdx.y;
    const int tid = threadIdx.x;
    const int cl = tid & 63, grp = tid >> 6;
    const int c = cs * 64 + cl;
    float s = 0.f, q = 0.f;
    for (int k = grp; k < 128; k += 4) {
        s += psum[((size_t)t * 128 + k) * 256 + c];
        q += psq [((size_t)t * 128 + k) * 256 + c];
    }
    __shared__ float ls[4][64], lq[4][64];
    ls[grp][cl] = s; lq[grp][cl] = q;
    __syncthreads();
    if (tid < 64) {
        s = ls[0][cl] + ls[1][cl] + ls[2][cl] + ls[3][cl];
        q = lq[0][cl] + lq[1][cl] + lq[2][cl] + lq[3][cl];
        float mean = s * (1.f / (float)M_);
        float var  = q * (1.f / (float)M_) - mean * mean;
        float inv  = rsqrtf(var + 1e-5f);
        float g = (t ? gc : gp)[c], be = (t ? bec : bep)[c];
        float sc = g * inv;
        ss[layerOff + t * 256 + c]       = sc;
        ss[layerOff + 512 + t * 256 + c] = be - mean * sc;
    }
}

// ---------------------------------------------------------------- GEMM2 (prefetch dbuf)
__global__ __launch_bounds__(512, 2) void gemm2f_kernel(
    const unsigned short* __restrict__ Y1,
    const unsigned short* __restrict__ Wb2,
    const float* __restrict__ ss,
    unsigned short* __restrict__ y2b,
    float* __restrict__ psum, float* __restrict__ psq)
{
    const int t  = blockIdx.y;
    const int m0 = blockIdx.x * 256;
    const unsigned short* Aw = Wb2 + (size_t)t * (OC_ * OC_);
    const unsigned short* By = Y1 + (size_t)t * M_ * OC_;

    __shared__ __align__(16) char smem[131072];
    __shared__ float Slds[256], Hlds[256];

    const int tid  = threadIdx.x;
    const int lane = tid & 63;
    const int wid  = tid >> 6;
    const int wc   = wid & 3;
    const int wm   = wid >> 2;
    const int srow = tid >> 3;
    const int k8   = (tid & 7) * 8;
    const int sk   = ((tid & 7) ^ (srow & 7)) * 8;
    const int kgrp = (lane >> 4) * 16;

    if (tid < 256) { Slds[tid] = ss[t * 256 + tid]; Hlds[tid] = ss[512 + t * 256 + tid]; }
    __syncthreads();

    f32x4 acc[4][8];
#pragma unroll
    for (int i = 0; i < 4; ++i)
#pragma unroll
        for (int j = 0; j < 8; ++j) acc[i][j] = f32x4{0.f, 0.f, 0.f, 0.f};

    auto stageA = [&](int buf, int kc) {
#pragma unroll
        for (int p = 0; p < 4; ++p)
            gload16(Aw + (size_t)(p * 64 + srow) * OC_ + kc + sk,
                    smem + buf * 32768 + p * 8192 + wid * 1024);
    };
    auto stageBY = [&](int buf, int kc) {
#pragma unroll
        for (int p = 0; p < 4; ++p) {
            int row = p * 64 + srow;
            ush8 yv = *(const ush8*)(By + (size_t)(m0 + row) * OC_ + kc + k8);
            ush8 ov;
#pragma unroll
            for (int j = 0; j < 8; ++j) {
                float y = bf2f(yv[j]);
                ov[j] = bf16rne(fmaxf(0.f, fmaf(y, Slds[kc + k8 + j], Hlds[kc + k8 + j])));
            }
            *(ush8*)(smem + 65536 + buf * 32768 + row * 128
                     + ((k8 * 2) ^ ((row & 7) << 4))) = ov;
        }
    };
    auto compute = [&](int buf) {
#pragma unroll
        for (int kk = 0; kk < 2; ++kk) {
            sh8 a[4], b[8];
#pragma unroll
            for (int f = 0; f < 4; ++f) {
                int ra = wc * 64 + (lane & 15) + f * 16;
                a[f] = *(const sh8*)(smem + buf * 32768 + ra * 128
                        + ((kk * 64 + kgrp) ^ ((ra & 7) << 4)));
            }
#pragma unroll
            for (int f = 0; f < 8; ++f) {
                int rb = wm * 128 + (lane & 15) + f * 16;
                b[f] = *(const sh8*)(smem + 65536 + buf * 32768 + rb * 128
                        + ((kk * 64 + kgrp) ^ ((rb & 7) << 4)));
            }
#pragma unroll
            for (int fc = 0; fc < 4; ++fc)
#pragma unroll
                for (int fm = 0; fm < 8; ++fm)
                    acc[fc][fm] = __builtin_amdgcn_mfma_f32_16x16x32_bf16(
                        a[fc], b[fm], acc[fc][fm], 0, 0, 0);
        }
    };

    stageA(0, 0); stageBY(0, 0);
    __syncthreads();
    int cur = 0;
    for (int step = 0; step < 4; ++step) {
        int kcn = (step + 1) * 64;
        if (step < 3) { stageA(cur ^ 1, kcn); stageBY(cur ^ 1, kcn); }
        compute(cur);
        __syncthreads();
        cur ^= 1;
    }

    const int mrow = m0 + wm * 128 + (lane & 15);
    const int chq  = (lane >> 4) * 4;
#pragma unroll
    for (int fm = 0; fm < 8; ++fm)
#pragma unroll
        for (int fc = 0; fc < 4; ++fc) {
            ush4 v;
#pragma unroll
            for (int r = 0; r < 4; ++r) v[r] = bf16rne(acc[fc][fm][r]);
            *(ush4*)(y2b + ((size_t)t * M_ + mrow + fm * 16) * OC_
                      + wc * 64 + fc * 16 + chq) = v;
        }

    float* sArr = (float*)smem;
    const int contrib = wm * 16 + (lane & 15);
#pragma unroll
    for (int ph = 0; ph < 2; ++ph) {
#pragma unroll
        for (int fc = 0; fc < 4; ++fc) {
            f32x4 s4;
#pragma unroll
            for (int r = 0; r < 4; ++r) {
                float s = 0.f;
#pragma unroll
                for (int fm = 0; fm < 8; ++fm) { float v = acc[fc][fm][r]; s += ph ? v * v : v; }
                s4[r] = s;
            }
            *(f32x4*)&sArr[contrib * 264 + wc * 64 + fc * 16 + chq] = s4;
        }
        __syncthreads();
        if (tid < 256) {
            float s = 0.f;
#pragma unroll
            for (int k = 0; k < 32; ++k) s += sArr[((k + tid) & 31) * 264 + tid];
            (ph ? psq : psum)[((size_t)t * 128 + blockIdx.x) * 256 + tid] = s;
        }
        __syncthreads();
    }
}

// ---------------------------------------------------------------- BN+ReLU + transpose
__global__ __launch_bounds__(256) void bnT_kernel(
    const unsigned short* __restrict__ y2b, const float* __restrict__ ss,
    float* __restrict__ out)
{
    const int z = blockIdx.z;
    const int t = z >> 3, b = z & 7;
    const int o0 = blockIdx.y * 64;
    const int n0 = blockIdx.x * 64;
    const int tid = threadIdx.x;
    __shared__ unsigned short tile[64][72];

    const unsigned short* src = y2b + ((size_t)t * M_ + (size_t)b * N_ + n0) * OC_ + o0;
#pragma unroll
    for (int it = 0; it < 2; ++it) {
        int u = it * 256 + tid;
        int m_l = u >> 3, o8 = (u & 7) * 8;
        *(ush8*)&tile[m_l][o8] = *(const ush8*)(src + (size_t)m_l * OC_ + o8);
    }
    __syncthreads();
#pragma unroll
    for (int it = 0; it < 4; ++it) {
        int v = it * 256 + tid;
        int o_l = v >> 4, n4 = (v & 15) * 4;
        int o = o0 + o_l;
        float sc = ss[1024 + t * 256 + o];
        float sh = ss[1536 + t * 256 + o];
        float4 w;
        w.x = fmaxf(0.f, fmaf(bf2f(tile[n4][o_l]),     sc, sh));
        w.y = fmaxf(0.f, fmaf(bf2f(tile[n4 + 1][o_l]), sc, sh));
        w.z = fmaxf(0.f, fmaf(bf2f(tile[n4 + 2][o_l]), sc, sh));
        w.w = fmaxf(0.f, fmaf(bf2f(tile[n4 + 3][o_l]), sc, sh));
        *(float4*)(out + (((size_t)t * B_ + b) * OC_ + o) * N_ + n0 + n4) = w;
    }
}

// ---------------------------------------------------------------- launch
extern "C" void kernel_launch(void* const* d_in, const int* in_sizes, int n_in,
                              void* d_out, int out_size, void* d_ws, size_t ws_size,
                              hipStream_t stream)
{
    const float* xyz1    = (const float*)d_in[0];
    const float* xyz2    = (const float*)d_in[1];
    const float* points1 = (const float*)d_in[2];
    const float* points2 = (const float*)d_in[3];
    const float* colors1 = (const float*)d_in[4];
    const float* colors2 = (const float*)d_in[5];
    const float* Wp1  = (const float*)d_in[6];
    const float* gp1  = (const float*)d_in[8];
    const float* bep1 = (const float*)d_in[9];
    const float* Wc1  = (const float*)d_in[10];
    const float* gc1  = (const float*)d_in[12];
    const float* bec1 = (const float*)d_in[13];
    const float* Wp2  = (const float*)d_in[14];
    const float* gp2  = (const float*)d_in[16];
    const float* bep2 = (const float*)d_in[17];
    const float* Wc2  = (const float*)d_in[18];
    const float* gc2  = (const float*)d_in[20];
    const float* bec2 = (const float*)d_in[21];
    // biases (d_in[7,11,15,19]) unused: constant channel shift cancels in BN.

    char* ws = (char*)d_ws;
    unsigned short* y2b  = (unsigned short*)(ws + 0);
    unsigned short* Xp   = (unsigned short*)(ws + 0);         // overlays y2b
    unsigned short* p2b  = (unsigned short*)(ws + 16777216);
    unsigned short* c2b  = (unsigned short*)(ws + 20971520);
    int*   idxw = (int*)  (ws + 25165824);
    float* wgtw = (float*)(ws + 25559040);
    unsigned short* Y1   = (unsigned short*)(ws + 33554432);
    unsigned short* Wb1  = (unsigned short*)(ws + 67108864);
    unsigned short* Wb2  = (unsigned short*)(ws + 67895296);
    float* psum = (float*)(ws + 68419584);
    float* psq  = (float*)(ws + 68681728);
    float* ssb  = (float*)(ws + 68943872);
    float* out  = (float*)d_out;

    front_kernel<<<6464, 256, 0, stream>>>(xyz1, xyz2, points1, colors1,
                                           points2, colors2, Wp1, Wc1, Wp2, Wc2,
                                           idxw, wgtw, p2b, c2b, Wb1, Wb2, Xp);
    gemm1f_kernel<<<256, 512, 0, stream>>>(Xp, p2b, c2b, idxw, wgtw,
                                           Wb1, Y1, psum, psq);
    reduce_kernel<<<dim3(2, 4), 256, 0, stream>>>(psum, psq, gp1, bep1, gc1, bec1, ssb, 0);
    gemm2f_kernel<<<dim3(128, 2), 512, 0, stream>>>(Y1, Wb2, ssb, y2b, psum, psq);
    reduce_kernel<<<dim3(2, 4), 256, 0, stream>>>(psum, psq, gp2, bep2, gc2, bec2, ssb, 1024);
    bnT_kernel<<<dim3(64, 4, 16), 256, 0, stream>>>(y2b, ssb, out);
}